// Round 2
// baseline (1267.322 us; speedup 1.0000x reference)
//
#include <hip/hip_runtime.h>

#define H_DIM 1024
#define T_DIM 4096
#define B_DIM 4
#define M_DIM (B_DIM * T_DIM)   // 16384
#define SCAN_C 256
#define SCAN_W 192

typedef __attribute__((ext_vector_type(8))) short short8;
typedef __attribute__((ext_vector_type(4))) float f32x4;

__device__ __forceinline__ unsigned short f2bf(float f) {
  unsigned int b = __float_as_uint(f);
  return (unsigned short)((b + 0x7FFFu + ((b >> 16) & 1u)) >> 16);
}
__device__ __forceinline__ float bf2f(unsigned short u) {
  return __uint_as_float(((unsigned int)u) << 16);
}

// ---------------- xs = x + time_shift(x); bf16 split (2- or 3-fold) ----------------
__global__ void xs_split_kernel(const float* __restrict__ x,
                                unsigned short* __restrict__ xs1,
                                unsigned short* __restrict__ xs2,
                                unsigned short* __restrict__ xs3,
                                int n4, int has3) {
  int i = blockIdx.x * blockDim.x + threadIdx.x;  // float4 index
  const int HV = H_DIM / 4;
  if (i >= n4) return;
  int m = i / HV;
  int t = m & (T_DIM - 1);   // slices start at batch boundaries, so t = m mod T
  float4 cur = reinterpret_cast<const float4*>(x)[i];
  float4 prev = make_float4(0.f, 0.f, 0.f, 0.f);
  if (t > 0) prev = reinterpret_cast<const float4*>(x)[i - HV];
  float s[4] = {cur.x + prev.x, cur.y + prev.y, cur.z + prev.z, cur.w + prev.w};
  unsigned short a1[4], a2[4], a3[4];
#pragma unroll
  for (int q = 0; q < 4; ++q) {
    float v = s[q];
    unsigned short h1 = f2bf(v);
    float f1 = bf2f(h1);
    unsigned short h2 = f2bf(v - f1);
    a1[q] = h1; a2[q] = h2;
    a3[q] = f2bf(v - f1 - bf2f(h2));
  }
  reinterpret_cast<ushort4*>(xs1)[i] = make_ushort4(a1[0], a1[1], a1[2], a1[3]);
  reinterpret_cast<ushort4*>(xs2)[i] = make_ushort4(a2[0], a2[1], a2[2], a2[3]);
  if (has3)
    reinterpret_cast<ushort4*>(xs3)[i] = make_ushort4(a3[0], a3[1], a3[2], a3[3]);
}

// ------------- weight prep: fold time_mix into W, bf16 splits --------------
__global__ void wprep_kernel(const float* __restrict__ Wrec, const float* __restrict__ Wkey,
                             const float* __restrict__ Wval, const float* __restrict__ Wout,
                             const float* __restrict__ tmk, const float* __restrict__ tmv,
                             const float* __restrict__ tmr,
                             unsigned short* __restrict__ WV1, unsigned short* __restrict__ WV2,
                             unsigned short* __restrict__ WR1, unsigned short* __restrict__ WR2,
                             unsigned short* __restrict__ WK1, unsigned short* __restrict__ WK2,
                             unsigned short* __restrict__ WK3,
                             unsigned short* __restrict__ WO1, unsigned short* __restrict__ WO2) {
  int i = blockIdx.x * blockDim.x + threadIdx.x;
  if (i >= H_DIM * H_DIM) return;
  int j = i & (H_DIM - 1);
  // key: triple split (WKV denominator has chaotic sensitivity: dout/dk ~ 2.5e5)
  float wk = Wkey[i] * tmk[j];
  unsigned short k1 = f2bf(wk); float kf1 = bf2f(k1);
  unsigned short k2 = f2bf(wk - kf1); float kf2 = bf2f(k2);
  WK1[i] = k1; WK2[i] = k2; WK3[i] = f2bf(wk - kf1 - kf2);
  float wv = Wval[i] * tmv[j];
  unsigned short v1 = f2bf(wv);
  WV1[i] = v1; WV2[i] = f2bf(wv - bf2f(v1));
  float wr = Wrec[i] * tmr[j];
  unsigned short r1 = f2bf(wr);
  WR1[i] = r1; WR2[i] = f2bf(wr - bf2f(r1));
  float wo = Wout[i];
  unsigned short o1 = f2bf(wo);
  WO1[i] = o1; WO2[i] = f2bf(wo - bf2f(o1));
}

// ------------------- multi-pass bf16 GEMM, C = sum_p A_p @ B_p^T -------------------
// A_p: [M,K] bf16 row-major; B_p: [N,K] bf16 row-major; C: [M,N] fp32 (omode 0) or bf16 (1).
struct GemmPasses {
  const unsigned short* A[6];
  const unsigned short* B[6];
  int n;
};

__global__ __launch_bounds__(256) void gemm_bt_kernel(GemmPasses P, void* __restrict__ Cout,
                                                      int N, int K,
                                                      const float* __restrict__ bias,
                                                      int omode) {
  __shared__ __attribute__((aligned(16))) unsigned char smem[16384];  // A 8KB | B 8KB
  const int tid = threadIdx.x;
  const int wave = tid >> 6;
  const int lane = tid & 63;
  const int brow = blockIdx.y << 7;
  const int bcol = blockIdx.x << 7;
  const int wr = (wave >> 1) << 6;
  const int wc = (wave & 1) << 6;
  const int frow = lane & 15;
  const int kg = lane >> 4;
  const int s_base = wave * 128;  // this wave's 16B LDS slots: [s_base, s_base+128)

  f32x4 acc[4][4];
#pragma unroll
  for (int i = 0; i < 4; ++i)
#pragma unroll
    for (int j = 0; j < 4; ++j)
      acc[i][j] = (f32x4){0.f, 0.f, 0.f, 0.f};

  for (int p = 0; p < P.n; ++p) {
    const unsigned short* Ag = P.A[p];
    const unsigned short* Bg = P.B[p];
    for (int kt = 0; kt < K; kt += 32) {
      // stage 128x32 bf16 tiles of A and B via global_load_lds (16B/lane), linear both sides
#pragma unroll
      for (int j = 0; j < 2; ++j) {
        int s = s_base + j * 64 + lane;
        int row = s >> 2;
        int c4 = s & 3;
        const unsigned short* srcA = Ag + (size_t)(brow + row) * K + kt + c4 * 8;
        const unsigned short* srcB = Bg + (size_t)(bcol + row) * K + kt + c4 * 8;
        unsigned int doff = (unsigned int)(s_base + j * 64) * 16u;  // wave-uniform
        __builtin_amdgcn_global_load_lds(
            (const __attribute__((address_space(1))) void*)srcA,
            (__attribute__((address_space(3))) void*)(smem + doff), 16, 0, 0);
        __builtin_amdgcn_global_load_lds(
            (const __attribute__((address_space(1))) void*)srcB,
            (__attribute__((address_space(3))) void*)(smem + 8192 + doff), 16, 0, 0);
      }
      __syncthreads();
      short8 af[4], bf[4];
#pragma unroll
      for (int i = 0; i < 4; ++i) {
        int r = wr + i * 16 + frow;
        af[i] = *reinterpret_cast<const short8*>(smem + (r * 64 + kg * 16));
        int rn = wc + i * 16 + frow;
        bf[i] = *reinterpret_cast<const short8*>(smem + (8192 + rn * 64 + kg * 16));
      }
#pragma unroll
      for (int i = 0; i < 4; ++i)
#pragma unroll
        for (int j = 0; j < 4; ++j)
          acc[i][j] = __builtin_amdgcn_mfma_f32_16x16x32_bf16(af[i], bf[j], acc[i][j], 0, 0, 0);
      __syncthreads();
    }
  }

  // epilogue: C/D layout col=lane&15, row=(lane>>4)*4+q
#pragma unroll
  for (int i = 0; i < 4; ++i) {
    int r0 = brow + wr + i * 16 + kg * 4;
#pragma unroll
    for (int j = 0; j < 4; ++j) {
      int c = bcol + wc + j * 16 + frow;
      if (omode == 0) {
        float bb = bias ? bias[c] : 0.f;
        float* C = (float*)Cout;
#pragma unroll
        for (int q = 0; q < 4; ++q)
          C[(size_t)(r0 + q) * N + c] = acc[i][j][q] + bb;
      } else {
        unsigned short* C = (unsigned short*)Cout;
#pragma unroll
        for (int q = 0; q < 4; ++q)
          C[(size_t)(r0 + q) * N + c] = f2bf(acc[i][j][q]);
      }
    }
  }
}

// ---------------- WKV scan (fp64 state), windowed chunks over T ----------------
// w = exp(-u), u>=0.5 -> 192-step warmup decays pre-window state by <= e^-96.
// k,v fp32 [.,H]; r bf16 [.,H]; outputs rw = sigmoid(r)*wkv as bf16 split pair.
__global__ void wkv_scan_kernel(const float* __restrict__ kbuf,
                                const float* __restrict__ vbuf,
                                const unsigned short* __restrict__ rbuf,
                                const float* __restrict__ tdec,
                                unsigned short* __restrict__ rw1,
                                unsigned short* __restrict__ rw2) {
  const int h = blockIdx.x * 64 + threadIdx.x;
  const int chunk = blockIdx.y;
  const int b = blockIdx.z;
  const int t0 = chunk * SCAN_C;
  const int tstart = (chunk == 0) ? 0 : (t0 - SCAN_W);
  double num, den;
  if (chunk == 0) { num = 1.0; den = 1.0; } else { num = 0.0; den = 0.0; }
  const double w = (double)tdec[h];
  size_t idx = ((size_t)b * T_DIM + tstart) * H_DIM + h;
  const int tend = t0 + SCAN_C;
  for (int t = tstart; t < tend; ++t) {
    double ck = (double)kbuf[idx];
    double cv = (double)vbuf[idx];
    if (t >= t0) {
      double o = (num + w * ck * den) / (den + w * ck);
      double rr = 1.0 / (1.0 + exp(-(double)bf2f(rbuf[idx])));
      float rw = (float)(rr * o);
      unsigned short h1 = f2bf(rw);
      rw1[idx] = h1;
      rw2[idx] = f2bf(rw - bf2f(h1));
    }
    double ek = exp(ck);
    num = w * num + ek * cv;
    den = w * den + ek;
    idx += H_DIM;
  }
}

// -------------------------------- host --------------------------------
static inline void run_gemm(const GemmPasses& P, void* C, int Mrows, int N, int K,
                            const float* bias, int omode, hipStream_t stream) {
  gemm_bt_kernel<<<dim3(N / 128, Mrows / 128), dim3(256), 0, stream>>>(P, C, N, K, bias, omode);
}

extern "C" void kernel_launch(void* const* d_in, const int* in_sizes, int n_in,
                              void* d_out, int out_size, void* d_ws, size_t ws_size,
                              hipStream_t stream) {
  const float* x    = (const float*)d_in[0];
  const float* tdec = (const float*)d_in[1];
  const float* tmk  = (const float*)d_in[2];
  const float* tmv  = (const float*)d_in[3];
  const float* tmr  = (const float*)d_in[4];
  const float* Wrec = (const float*)d_in[5];
  const float* Wkey = (const float*)d_in[6];
  const float* Wval = (const float*)d_in[7];
  const float* Wout = (const float*)d_in[8];
  const float* bout = (const float*)d_in[9];
  float* out = (float*)d_out;
  unsigned char* ws = (unsigned char*)d_ws;

  const size_t W2 = (size_t)H_DIM * H_DIM * 2;           // 2MB per weight split
  const size_t BF_FULL = (size_t)M_DIM * H_DIM * 2;      // 32MB bf16 [M,H]
  const size_t F_FULL  = (size_t)M_DIM * H_DIM * 4;      // 64MB fp32 [M,H]
  const size_t BF_B = BF_FULL / B_DIM;                   // 8MB per-batch bf16
  const size_t F_B  = F_FULL / B_DIM;                    // 16MB per-batch fp32

  const size_t NEED_A = 3 * BF_FULL + F_FULL + BF_FULL + 9 * W2;  // 210MB
  const size_t NEED_B = 3 * BF_B + F_B + BF_B + 9 * W2;           // 66MB
  const size_t NEED_C = NEED_B - BF_B;                            // 58MB

  int plan;
  size_t szXS, szV, szR;
  if (ws_size >= NEED_A)      { plan = 0; szXS = BF_FULL; szV = F_FULL; szR = BF_FULL; }
  else if (ws_size >= NEED_B) { plan = 1; szXS = BF_B; szV = F_B; szR = BF_B; }
  else if (ws_size >= NEED_C) { plan = 2; szXS = BF_B; szV = F_B; szR = BF_B; }
  else return;  // workspace unusably small; visible as unchanged-absmax fail
  const int has3 = (plan != 2);

  size_t off = 0;
  unsigned short* XS1 = (unsigned short*)(ws + off); off += szXS;
  unsigned short* XS2 = (unsigned short*)(ws + off); off += szXS;
  unsigned short* XS3 = (unsigned short*)(ws + off); if (has3) off += szXS;
  float*          V   = (float*)(ws + off);          off += szV;
  unsigned short* R   = (unsigned short*)(ws + off); off += szR;
  unsigned short* WV1 = (unsigned short*)(ws + off); off += W2;
  unsigned short* WV2 = (unsigned short*)(ws + off); off += W2;
  unsigned short* WR1 = (unsigned short*)(ws + off); off += W2;
  unsigned short* WR2 = (unsigned short*)(ws + off); off += W2;
  unsigned short* WK1 = (unsigned short*)(ws + off); off += W2;
  unsigned short* WK2 = (unsigned short*)(ws + off); off += W2;
  unsigned short* WK3 = (unsigned short*)(ws + off); off += W2;
  unsigned short* WO1 = (unsigned short*)(ws + off); off += W2;
  unsigned short* WO2 = (unsigned short*)(ws + off); off += W2;

  wprep_kernel<<<dim3(H_DIM * H_DIM / 256), dim3(256), 0, stream>>>(
      Wrec, Wkey, Wval, Wout, tmk, tmv, tmr, WV1, WV2, WR1, WR2, WK1, WK2, WK3, WO1, WO2);

  GemmPasses Pv, Pr, Pk, Po;
  Pv.A[0]=XS1; Pv.B[0]=WV1;  Pv.A[1]=XS1; Pv.B[1]=WV2;  Pv.A[2]=XS2; Pv.B[2]=WV1;
  Pv.A[3]=XS1; Pv.B[3]=WV1;  Pv.A[4]=XS1; Pv.B[4]=WV1;  Pv.A[5]=XS1; Pv.B[5]=WV1;  Pv.n=3;
  Pr.A[0]=XS1; Pr.B[0]=WR1;  Pr.A[1]=XS1; Pr.B[1]=WR2;  Pr.A[2]=XS2; Pr.B[2]=WR1;
  Pr.A[3]=XS1; Pr.B[3]=WR1;  Pr.A[4]=XS1; Pr.B[4]=WR1;  Pr.A[5]=XS1; Pr.B[5]=WR1;  Pr.n=3;
  Pk.A[0]=XS1; Pk.B[0]=WK1;  Pk.A[1]=XS1; Pk.B[1]=WK2;  Pk.A[2]=XS2; Pk.B[2]=WK1;
  Pk.A[3]=XS2; Pk.B[3]=WK2;  Pk.A[4]=XS1; Pk.B[4]=WK3;  Pk.A[5]=XS3; Pk.B[5]=WK1;
  Pk.n = has3 ? 6 : 5;
  // rw splits reuse XS1/XS2 (dead after the k GEMM)
  Po.A[0]=XS1; Po.B[0]=WO1;  Po.A[1]=XS1; Po.B[1]=WO2;  Po.A[2]=XS2; Po.B[2]=WO1;
  Po.A[3]=XS1; Po.B[3]=WO1;  Po.A[4]=XS1; Po.B[4]=WO1;  Po.A[5]=XS1; Po.B[5]=WO1;  Po.n=3;

  if (plan == 0) {
    // full-M pipeline; k lives in d_out (dead before the final GEMM overwrites it)
    int n4 = M_DIM * (H_DIM / 4);
    xs_split_kernel<<<dim3(n4 / 256), dim3(256), 0, stream>>>(x, XS1, XS2, XS3, n4, 1);
    run_gemm(Pv, V,   M_DIM, H_DIM, H_DIM, nullptr, 0, stream);
    run_gemm(Pr, R,   M_DIM, H_DIM, H_DIM, nullptr, 1, stream);
    run_gemm(Pk, out, M_DIM, H_DIM, H_DIM, nullptr, 0, stream);
    wkv_scan_kernel<<<dim3(H_DIM / 64, T_DIM / SCAN_C, B_DIM), dim3(64), 0, stream>>>(
        out, V, R, tdec, XS1, XS2);
    run_gemm(Po, out, M_DIM, H_DIM, H_DIM, bout, 0, stream);
  } else {
    // per-batch chunks: each b starts from the true init state, no warmup needed
    for (int b = 0; b < B_DIM; ++b) {
      const float* xb = x + (size_t)b * T_DIM * H_DIM;
      float* kb = out + (size_t)b * T_DIM * H_DIM;
      int n4 = T_DIM * (H_DIM / 4);
      xs_split_kernel<<<dim3(n4 / 256), dim3(256), 0, stream>>>(xb, XS1, XS2, XS3, n4, has3);
      run_gemm(Pv, V,  T_DIM, H_DIM, H_DIM, nullptr, 0, stream);
      run_gemm(Pr, R,  T_DIM, H_DIM, H_DIM, nullptr, 1, stream);
      run_gemm(Pk, kb, T_DIM, H_DIM, H_DIM, nullptr, 0, stream);
      wkv_scan_kernel<<<dim3(H_DIM / 64, T_DIM / SCAN_C, 1), dim3(64), 0, stream>>>(
          kb, V, R, tdec, XS1, XS2);
      run_gemm(Po, kb, T_DIM, H_DIM, H_DIM, bout, 0, stream);
    }
  }
}

// Round 3
// 871.845 us; speedup vs baseline: 1.4536x; 1.4536x over previous
//
#include <hip/hip_runtime.h>

#define H_DIM 1024
#define T_DIM 4096
#define B_DIM 4
#define M_DIM (B_DIM * T_DIM)   // 16384
#define SCAN_C 128
#define SCAN_W 96

typedef __attribute__((ext_vector_type(8))) short short8;
typedef __attribute__((ext_vector_type(4))) float f32x4;

__device__ __forceinline__ unsigned short f2bf(float f) {
  unsigned int b = __float_as_uint(f);
  return (unsigned short)((b + 0x7FFFu + ((b >> 16) & 1u)) >> 16);
}
__device__ __forceinline__ float bf2f(unsigned short u) {
  return __uint_as_float(((unsigned int)u) << 16);
}

// fast fp64 exp: 2^n * e^y, |y| <= ln2/2, Taylor deg-9 (rel err ~7e-12; the WKV
// amplification budget needs < 1e-8, libm fp64 exp is ~2x the instructions)
__device__ __forceinline__ double fast_exp64(double x) {
  const double L2E = 1.4426950408889634074;
  const double LN2 = 0.69314718055994530942;
  double z = x * L2E;
  double n = rint(z);
  double y = (z - n) * LN2;
  double p = 2.7557319223985890653e-6;      // 1/9!
  p = fma(p, y, 2.4801587301587301566e-5);  // 1/8!
  p = fma(p, y, 1.9841269841269841253e-4);  // 1/7!
  p = fma(p, y, 1.3888888888888889419e-3);  // 1/6!
  p = fma(p, y, 8.3333333333333332177e-3);  // 1/5!
  p = fma(p, y, 4.1666666666666664354e-2);  // 1/4!
  p = fma(p, y, 1.6666666666666665741e-1);  // 1/3!
  p = fma(p, y, 0.5);
  p = fma(p, y, 1.0);
  p = fma(p, y, 1.0);
  long long bits = ((long long)(1023 + (int)n)) << 52;
  return p * __longlong_as_double(bits);
}

// ---------------- xs = x + time_shift(x); bf16 split (2- or 3-fold) ----------------
__global__ void xs_split_kernel(const float* __restrict__ x,
                                unsigned short* __restrict__ xs1,
                                unsigned short* __restrict__ xs2,
                                unsigned short* __restrict__ xs3,
                                int n4, int has3) {
  int i = blockIdx.x * blockDim.x + threadIdx.x;  // float4 index
  const int HV = H_DIM / 4;
  if (i >= n4) return;
  int m = i / HV;
  int t = m & (T_DIM - 1);   // slices start at batch boundaries, so t = m mod T
  float4 cur = reinterpret_cast<const float4*>(x)[i];
  float4 prev = make_float4(0.f, 0.f, 0.f, 0.f);
  if (t > 0) prev = reinterpret_cast<const float4*>(x)[i - HV];
  float s[4] = {cur.x + prev.x, cur.y + prev.y, cur.z + prev.z, cur.w + prev.w};
  unsigned short a1[4], a2[4], a3[4];
#pragma unroll
  for (int q = 0; q < 4; ++q) {
    float v = s[q];
    unsigned short h1 = f2bf(v);
    float f1 = bf2f(h1);
    unsigned short h2 = f2bf(v - f1);
    a1[q] = h1; a2[q] = h2;
    a3[q] = f2bf(v - f1 - bf2f(h2));
  }
  reinterpret_cast<ushort4*>(xs1)[i] = make_ushort4(a1[0], a1[1], a1[2], a1[3]);
  reinterpret_cast<ushort4*>(xs2)[i] = make_ushort4(a2[0], a2[1], a2[2], a2[3]);
  if (has3)
    reinterpret_cast<ushort4*>(xs3)[i] = make_ushort4(a3[0], a3[1], a3[2], a3[3]);
}

// ------------- weight prep: fold time_mix into W, bf16 splits --------------
__global__ void wprep_kernel(const float* __restrict__ Wrec, const float* __restrict__ Wkey,
                             const float* __restrict__ Wval, const float* __restrict__ Wout,
                             const float* __restrict__ tmk, const float* __restrict__ tmv,
                             const float* __restrict__ tmr,
                             unsigned short* __restrict__ WV1, unsigned short* __restrict__ WV2,
                             unsigned short* __restrict__ WR1, unsigned short* __restrict__ WR2,
                             unsigned short* __restrict__ WK1, unsigned short* __restrict__ WK2,
                             unsigned short* __restrict__ WK3,
                             unsigned short* __restrict__ WO1, unsigned short* __restrict__ WO2) {
  int i = blockIdx.x * blockDim.x + threadIdx.x;
  if (i >= H_DIM * H_DIM) return;
  int j = i & (H_DIM - 1);
  // key: triple split (WKV denominator has chaotic sensitivity to k)
  float wk = Wkey[i] * tmk[j];
  unsigned short k1 = f2bf(wk); float kf1 = bf2f(k1);
  unsigned short k2 = f2bf(wk - kf1); float kf2 = bf2f(k2);
  WK1[i] = k1; WK2[i] = k2; WK3[i] = f2bf(wk - kf1 - kf2);
  float wv = Wval[i] * tmv[j];
  unsigned short v1 = f2bf(wv);
  WV1[i] = v1; WV2[i] = f2bf(wv - bf2f(v1));
  float wr = Wrec[i] * tmr[j];
  unsigned short r1 = f2bf(wr);
  WR1[i] = r1; WR2[i] = f2bf(wr - bf2f(r1));
  float wo = Wout[i];
  unsigned short o1 = f2bf(wo);
  WO1[i] = o1; WO2[i] = f2bf(wo - bf2f(o1));
}

// ------------------- multi-pass bf16 GEMM, C = sum_p A_p @ B_p^T -------------------
// A_p: [M,K] bf16 row-major; B_p: [N,K] bf16 row-major; C: [M,N] fp32 (omode 0) or bf16 (1).
// Pass lists are ordered small-magnitude first so the fp32 accumulator only takes
// full-magnitude roundings during the final (dominant) pass.
struct GemmPasses {
  const unsigned short* A[6];
  const unsigned short* B[6];
  int n;
};

__global__ __launch_bounds__(256) void gemm_bt_kernel(GemmPasses P, void* __restrict__ Cout,
                                                      int N, int K,
                                                      const float* __restrict__ bias,
                                                      int omode) {
  __shared__ __attribute__((aligned(16))) unsigned char smem[16384];  // A 8KB | B 8KB
  const int tid = threadIdx.x;
  const int wave = tid >> 6;
  const int lane = tid & 63;
  // T1: XCD-aware swizzle (nwg % 8 == 0 for all our launches -> bijective)
  const int nwg = gridDim.x * gridDim.y;
  const int wg = blockIdx.y * gridDim.x + blockIdx.x;
  const int cpx = nwg >> 3;
  const int swz = (wg & 7) * cpx + (wg >> 3);
  const int brow = (swz / gridDim.x) << 7;
  const int bcol = (swz % gridDim.x) << 7;
  const int wr = (wave >> 1) << 6;
  const int wc = (wave & 1) << 6;
  const int frow = lane & 15;
  const int kg = lane >> 4;
  const int s_base = wave * 128;  // this wave's 16B LDS slots: [s_base, s_base+128)

  f32x4 acc[4][4];
#pragma unroll
  for (int i = 0; i < 4; ++i)
#pragma unroll
    for (int j = 0; j < 4; ++j)
      acc[i][j] = (f32x4){0.f, 0.f, 0.f, 0.f};

  for (int p = 0; p < P.n; ++p) {
    const unsigned short* Ag = P.A[p];
    const unsigned short* Bg = P.B[p];
    for (int kt = 0; kt < K; kt += 32) {
      // stage 128x32 bf16 tiles of A and B via global_load_lds (16B/lane), linear both sides
#pragma unroll
      for (int j = 0; j < 2; ++j) {
        int s = s_base + j * 64 + lane;
        int row = s >> 2;
        int c4 = s & 3;
        const unsigned short* srcA = Ag + (size_t)(brow + row) * K + kt + c4 * 8;
        const unsigned short* srcB = Bg + (size_t)(bcol + row) * K + kt + c4 * 8;
        unsigned int doff = (unsigned int)(s_base + j * 64) * 16u;  // wave-uniform
        __builtin_amdgcn_global_load_lds(
            (const __attribute__((address_space(1))) void*)srcA,
            (__attribute__((address_space(3))) void*)(smem + doff), 16, 0, 0);
        __builtin_amdgcn_global_load_lds(
            (const __attribute__((address_space(1))) void*)srcB,
            (__attribute__((address_space(3))) void*)(smem + 8192 + doff), 16, 0, 0);
      }
      __syncthreads();
      short8 af[4], bf[4];
#pragma unroll
      for (int i = 0; i < 4; ++i) {
        int r = wr + i * 16 + frow;
        af[i] = *reinterpret_cast<const short8*>(smem + (r * 64 + kg * 16));
        int rn = wc + i * 16 + frow;
        bf[i] = *reinterpret_cast<const short8*>(smem + (8192 + rn * 64 + kg * 16));
      }
#pragma unroll
      for (int i = 0; i < 4; ++i)
#pragma unroll
        for (int j = 0; j < 4; ++j)
          acc[i][j] = __builtin_amdgcn_mfma_f32_16x16x32_bf16(af[i], bf[j], acc[i][j], 0, 0, 0);
      __syncthreads();
    }
  }

  // epilogue: C/D layout col=lane&15, row=(lane>>4)*4+q
#pragma unroll
  for (int i = 0; i < 4; ++i) {
    int r0 = brow + wr + i * 16 + kg * 4;
#pragma unroll
    for (int j = 0; j < 4; ++j) {
      int c = bcol + wc + j * 16 + frow;
      if (omode == 0) {
        float bb = bias ? bias[c] : 0.f;
        float* C = (float*)Cout;
#pragma unroll
        for (int q = 0; q < 4; ++q)
          C[(size_t)(r0 + q) * N + c] = acc[i][j][q] + bb;
      } else {
        unsigned short* C = (unsigned short*)Cout;
#pragma unroll
        for (int q = 0; q < 4; ++q)
          C[(size_t)(r0 + q) * N + c] = f2bf(acc[i][j][q]);
      }
    }
  }
}

// ---------------- WKV scan (fp64 state), windowed chunks over T ----------------
// w = exp(-u), u>=0.5 -> 96-step warmup decays pre-window state by <= e^-48.
// Prefetched loads + inline fp64 exp; div & sigmoid in fp32 AFTER the fp64
// cancellation-critical sums (out rel err ~6e-8 from the conversion).
__global__ void wkv_scan_kernel(const float* __restrict__ kbuf,
                                const float* __restrict__ vbuf,
                                const unsigned short* __restrict__ rbuf,
                                const float* __restrict__ tdec,
                                unsigned short* __restrict__ rw1,
                                unsigned short* __restrict__ rw2) {
  const int h = blockIdx.x * 64 + threadIdx.x;
  const int chunk = blockIdx.y;
  const int b = blockIdx.z;
  const int t0 = chunk * SCAN_C;
  const int tstart = (chunk == 0) ? 0 : (t0 - SCAN_W);
  const int tend = t0 + SCAN_C;
  double num, den;
  if (chunk == 0) { num = 1.0; den = 1.0; } else { num = 0.0; den = 0.0; }
  const double w = (double)tdec[h];
  size_t idx = ((size_t)b * T_DIM + tstart) * H_DIM + h;
  float kc = kbuf[idx];
  float vc = vbuf[idx];
  unsigned short rc = rbuf[idx];
  for (int t = tstart; t < tend; ++t) {
    // prefetch next step (clamped address; last-iter clamp avoids OOB)
    size_t idxn = idx + ((t + 1 < tend) ? H_DIM : 0);
    float kn = kbuf[idxn];
    float vn = vbuf[idxn];
    unsigned short rn = rbuf[idxn];
    double ck = (double)kc;
    if (t >= t0) {
      double p = w * ck;
      double A = fma(p, den, num);
      double Bd = den + p;
      float outf = (float)A / (float)Bd;
      float rr = 1.0f / (1.0f + __expf(-bf2f(rc)));
      float rw = rr * outf;
      unsigned short h1 = f2bf(rw);
      rw1[idx] = h1;
      rw2[idx] = f2bf(rw - bf2f(h1));
    }
    double ek = fast_exp64(ck);
    num = fma(w, num, ek * (double)vc);
    den = fma(w, den, ek);
    kc = kn; vc = vn; rc = rn;
    idx += H_DIM;
  }
}

// -------------------------------- host --------------------------------
static inline void run_gemm(const GemmPasses& P, void* C, int Mrows, int N, int K,
                            const float* bias, int omode, hipStream_t stream) {
  gemm_bt_kernel<<<dim3(N / 128, Mrows / 128), dim3(256), 0, stream>>>(P, C, N, K, bias, omode);
}

extern "C" void kernel_launch(void* const* d_in, const int* in_sizes, int n_in,
                              void* d_out, int out_size, void* d_ws, size_t ws_size,
                              hipStream_t stream) {
  const float* x    = (const float*)d_in[0];
  const float* tdec = (const float*)d_in[1];
  const float* tmk  = (const float*)d_in[2];
  const float* tmv  = (const float*)d_in[3];
  const float* tmr  = (const float*)d_in[4];
  const float* Wrec = (const float*)d_in[5];
  const float* Wkey = (const float*)d_in[6];
  const float* Wval = (const float*)d_in[7];
  const float* Wout = (const float*)d_in[8];
  const float* bout = (const float*)d_in[9];
  float* out = (float*)d_out;
  unsigned char* ws = (unsigned char*)d_ws;

  const size_t W2 = (size_t)H_DIM * H_DIM * 2;           // 2MB per weight split
  const size_t BF_FULL = (size_t)M_DIM * H_DIM * 2;      // 32MB bf16 [M,H]
  const size_t F_FULL  = (size_t)M_DIM * H_DIM * 4;      // 64MB fp32 [M,H]
  const size_t BF_B = BF_FULL / B_DIM;                   // 8MB per-batch bf16
  const size_t F_B  = F_FULL / B_DIM;                    // 16MB per-batch fp32

  const size_t NEED_A = 3 * BF_FULL + F_FULL + BF_FULL + 9 * W2;  // 210MB
  const size_t NEED_B = 3 * BF_B + F_B + BF_B + 9 * W2;           // 66MB
  const size_t NEED_C = NEED_B - BF_B;                            // 58MB

  int plan;
  size_t szXS, szV, szR;
  if (ws_size >= NEED_A)      { plan = 0; szXS = BF_FULL; szV = F_FULL; szR = BF_FULL; }
  else if (ws_size >= NEED_B) { plan = 1; szXS = BF_B; szV = F_B; szR = BF_B; }
  else if (ws_size >= NEED_C) { plan = 2; szXS = BF_B; szV = F_B; szR = BF_B; }
  else return;  // workspace unusably small; visible as unchanged-absmax fail
  const int has3 = (plan != 2);

  size_t off = 0;
  unsigned short* XS1 = (unsigned short*)(ws + off); off += szXS;
  unsigned short* XS2 = (unsigned short*)(ws + off); off += szXS;
  unsigned short* XS3 = (unsigned short*)(ws + off); if (has3) off += szXS;
  float*          V   = (float*)(ws + off);          off += szV;
  unsigned short* R   = (unsigned short*)(ws + off); off += szR;
  unsigned short* WV1 = (unsigned short*)(ws + off); off += W2;
  unsigned short* WV2 = (unsigned short*)(ws + off); off += W2;
  unsigned short* WR1 = (unsigned short*)(ws + off); off += W2;
  unsigned short* WR2 = (unsigned short*)(ws + off); off += W2;
  unsigned short* WK1 = (unsigned short*)(ws + off); off += W2;
  unsigned short* WK2 = (unsigned short*)(ws + off); off += W2;
  unsigned short* WK3 = (unsigned short*)(ws + off); off += W2;
  unsigned short* WO1 = (unsigned short*)(ws + off); off += W2;
  unsigned short* WO2 = (unsigned short*)(ws + off); off += W2;

  wprep_kernel<<<dim3(H_DIM * H_DIM / 256), dim3(256), 0, stream>>>(
      Wrec, Wkey, Wval, Wout, tmk, tmv, tmr, WV1, WV2, WR1, WR2, WK1, WK2, WK3, WO1, WO2);

  // pass lists ordered small -> large magnitude (accumulator rounding control)
  GemmPasses Pv, Pr, Pk, Po;
  Pv.A[0]=XS1; Pv.B[0]=WV2;  Pv.A[1]=XS2; Pv.B[1]=WV1;  Pv.A[2]=XS1; Pv.B[2]=WV1;
  Pv.A[3]=XS1; Pv.B[3]=WV1;  Pv.A[4]=XS1; Pv.B[4]=WV1;  Pv.A[5]=XS1; Pv.B[5]=WV1;  Pv.n=3;
  Pr.A[0]=XS1; Pr.B[0]=WR2;  Pr.A[1]=XS2; Pr.B[1]=WR1;  Pr.A[2]=XS1; Pr.B[2]=WR1;
  Pr.A[3]=XS1; Pr.B[3]=WR1;  Pr.A[4]=XS1; Pr.B[4]=WR1;  Pr.A[5]=XS1; Pr.B[5]=WR1;  Pr.n=3;
  if (has3) {
    Pk.A[0]=XS2; Pk.B[0]=WK2;  Pk.A[1]=XS1; Pk.B[1]=WK3;  Pk.A[2]=XS3; Pk.B[2]=WK1;
    Pk.A[3]=XS1; Pk.B[3]=WK2;  Pk.A[4]=XS2; Pk.B[4]=WK1;  Pk.A[5]=XS1; Pk.B[5]=WK1;
    Pk.n = 6;
  } else {
    Pk.A[0]=XS2; Pk.B[0]=WK2;  Pk.A[1]=XS1; Pk.B[1]=WK3;  Pk.A[2]=XS1; Pk.B[2]=WK2;
    Pk.A[3]=XS2; Pk.B[3]=WK1;  Pk.A[4]=XS1; Pk.B[4]=WK1;  Pk.A[5]=XS1; Pk.B[5]=WK1;
    Pk.n = 5;
  }
  // rw splits reuse XS1/XS2 (dead after the k GEMM)
  Po.A[0]=XS1; Po.B[0]=WO2;  Po.A[1]=XS2; Po.B[1]=WO1;  Po.A[2]=XS1; Po.B[2]=WO1;
  Po.A[3]=XS1; Po.B[3]=WO1;  Po.A[4]=XS1; Po.B[4]=WO1;  Po.A[5]=XS1; Po.B[5]=WO1;  Po.n=3;

  if (plan == 0) {
    // full-M pipeline; k lives in d_out (dead before the final GEMM overwrites it)
    int n4 = M_DIM * (H_DIM / 4);
    xs_split_kernel<<<dim3(n4 / 256), dim3(256), 0, stream>>>(x, XS1, XS2, XS3, n4, 1);
    run_gemm(Pv, V,   M_DIM, H_DIM, H_DIM, nullptr, 0, stream);
    run_gemm(Pr, R,   M_DIM, H_DIM, H_DIM, nullptr, 1, stream);
    run_gemm(Pk, out, M_DIM, H_DIM, H_DIM, nullptr, 0, stream);
    wkv_scan_kernel<<<dim3(H_DIM / 64, T_DIM / SCAN_C, B_DIM), dim3(64), 0, stream>>>(
        out, V, R, tdec, XS1, XS2);
    run_gemm(Po, out, M_DIM, H_DIM, H_DIM, bout, 0, stream);
  } else {
    // per-batch chunks: each b starts from the true init state, no warmup needed
    for (int b = 0; b < B_DIM; ++b) {
      const float* xb = x + (size_t)b * T_DIM * H_DIM;
      float* kb = out + (size_t)b * T_DIM * H_DIM;
      int n4 = T_DIM * (H_DIM / 4);
      xs_split_kernel<<<dim3(n4 / 256), dim3(256), 0, stream>>>(xb, XS1, XS2, XS3, n4, has3);
      run_gemm(Pv, V,  T_DIM, H_DIM, H_DIM, nullptr, 0, stream);
      run_gemm(Pr, R,  T_DIM, H_DIM, H_DIM, nullptr, 1, stream);
      run_gemm(Pk, kb, T_DIM, H_DIM, H_DIM, nullptr, 0, stream);
      wkv_scan_kernel<<<dim3(H_DIM / 64, T_DIM / SCAN_C, 1), dim3(64), 0, stream>>>(
          kb, V, R, tdec, XS1, XS2);
      run_gemm(Po, kb, T_DIM, H_DIM, H_DIM, bout, 0, stream);
    }
  }
}

// Round 4
// 685.024 us; speedup vs baseline: 1.8500x; 1.2727x over previous
//
#include <hip/hip_runtime.h>

#define H_DIM 1024
#define T_DIM 4096
#define B_DIM 4
#define M_DIM (B_DIM * T_DIM)   // 16384
#define SCAN_C 128
#define SCAN_W 96

typedef __attribute__((ext_vector_type(8))) short short8;
typedef __attribute__((ext_vector_type(4))) float f32x4;

__device__ __forceinline__ unsigned short f2bf(float f) {
  unsigned int b = __float_as_uint(f);
  return (unsigned short)((b + 0x7FFFu + ((b >> 16) & 1u)) >> 16);
}
__device__ __forceinline__ float bf2f(unsigned short u) {
  return __uint_as_float(((unsigned int)u) << 16);
}

__device__ __forceinline__ double fast_exp64(double x) {
  const double L2E = 1.4426950408889634074;
  const double LN2 = 0.69314718055994530942;
  double z = x * L2E;
  double n = rint(z);
  double y = (z - n) * LN2;
  double p = 2.7557319223985890653e-6;
  p = fma(p, y, 2.4801587301587301566e-5);
  p = fma(p, y, 1.9841269841269841253e-4);
  p = fma(p, y, 1.3888888888888889419e-3);
  p = fma(p, y, 8.3333333333333332177e-3);
  p = fma(p, y, 4.1666666666666664354e-2);
  p = fma(p, y, 1.6666666666666665741e-1);
  p = fma(p, y, 0.5);
  p = fma(p, y, 1.0);
  p = fma(p, y, 1.0);
  long long bits = ((long long)(1023 + (int)n)) << 52;
  return p * __longlong_as_double(bits);
}

// ---------------- xs = x + time_shift(x); bf16 split ----------------
__global__ void xs_split_kernel(const float* __restrict__ x,
                                unsigned short* __restrict__ xs1,
                                unsigned short* __restrict__ xs2,
                                unsigned short* __restrict__ xs3,
                                int n4, int has3) {
  int i = blockIdx.x * blockDim.x + threadIdx.x;
  const int HV = H_DIM / 4;
  if (i >= n4) return;
  int m = i / HV;
  int t = m & (T_DIM - 1);
  float4 cur = reinterpret_cast<const float4*>(x)[i];
  float4 prev = make_float4(0.f, 0.f, 0.f, 0.f);
  if (t > 0) prev = reinterpret_cast<const float4*>(x)[i - HV];
  float s[4] = {cur.x + prev.x, cur.y + prev.y, cur.z + prev.z, cur.w + prev.w};
  unsigned short a1[4], a2[4], a3[4];
#pragma unroll
  for (int q = 0; q < 4; ++q) {
    float v = s[q];
    unsigned short h1 = f2bf(v);
    float f1 = bf2f(h1);
    unsigned short h2 = f2bf(v - f1);
    a1[q] = h1; a2[q] = h2;
    a3[q] = f2bf(v - f1 - bf2f(h2));
  }
  reinterpret_cast<ushort4*>(xs1)[i] = make_ushort4(a1[0], a1[1], a1[2], a1[3]);
  reinterpret_cast<ushort4*>(xs2)[i] = make_ushort4(a2[0], a2[1], a2[2], a2[3]);
  if (has3)
    reinterpret_cast<ushort4*>(xs3)[i] = make_ushort4(a3[0], a3[1], a3[2], a3[3]);
}

// ------------- weight prep -------------
__global__ void wprep_kernel(const float* __restrict__ Wrec, const float* __restrict__ Wkey,
                             const float* __restrict__ Wval, const float* __restrict__ Wout,
                             const float* __restrict__ tmk, const float* __restrict__ tmv,
                             const float* __restrict__ tmr,
                             unsigned short* __restrict__ WV1, unsigned short* __restrict__ WV2,
                             unsigned short* __restrict__ WR1, unsigned short* __restrict__ WR2,
                             unsigned short* __restrict__ WK1, unsigned short* __restrict__ WK2,
                             unsigned short* __restrict__ WK3,
                             unsigned short* __restrict__ WO1, unsigned short* __restrict__ WO2) {
  int i = blockIdx.x * blockDim.x + threadIdx.x;
  if (i >= H_DIM * H_DIM) return;
  int j = i & (H_DIM - 1);
  float wk = Wkey[i] * tmk[j];
  unsigned short k1 = f2bf(wk); float kf1 = bf2f(k1);
  unsigned short k2 = f2bf(wk - kf1); float kf2 = bf2f(k2);
  WK1[i] = k1; WK2[i] = k2; WK3[i] = f2bf(wk - kf1 - kf2);
  float wv = Wval[i] * tmv[j];
  unsigned short v1 = f2bf(wv);
  WV1[i] = v1; WV2[i] = f2bf(wv - bf2f(v1));
  float wr = Wrec[i] * tmr[j];
  unsigned short r1 = f2bf(wr);
  WR1[i] = r1; WR2[i] = f2bf(wr - bf2f(r1));
  float wo = Wout[i];
  unsigned short o1 = f2bf(wo);
  WO1[i] = o1; WO2[i] = f2bf(wo - bf2f(o1));
}

// =================== 256x256 8-phase multi-pass bf16 GEMM ===================
// C = sum_p A_p @ B_p^T.  A_p [M,1024] bf16, B_p [N,1024] bf16 row-major.
// 8 waves (2Mx4N), BK=64, LDS 128KB = 8 half-slots (A-k0,B-k0,A-k1,B-k1 per tile),
// stage-lead 7 halves, vmcnt(6) per K-tile (T3+T4), swizzled LDS (T2), setprio (T5).
struct GemmPasses {
  const unsigned short* A[6];
  const unsigned short* B[6];
  int n;
};

#define GBAR() do { asm volatile("" ::: "memory"); __builtin_amdgcn_sched_barrier(0); \
                    __builtin_amdgcn_s_barrier(); \
                    __builtin_amdgcn_sched_barrier(0); asm volatile("" ::: "memory"); } while (0)
#define WAIT_VM6() asm volatile("s_waitcnt vmcnt(6)" ::: "memory")
#define WAIT_VM0() asm volatile("s_waitcnt vmcnt(0)" ::: "memory")

__device__ __forceinline__ const unsigned short* selA(const GemmPasses& P, int p) {
  const unsigned short* r = P.A[0];
  if (p == 1) r = P.A[1];
  if (p == 2) r = P.A[2];
  if (p == 3) r = P.A[3];
  if (p == 4) r = P.A[4];
  if (p == 5) r = P.A[5];
  return r;
}
__device__ __forceinline__ const unsigned short* selB(const GemmPasses& P, int p) {
  const unsigned short* r = P.B[0];
  if (p == 1) r = P.B[1];
  if (p == 2) r = P.B[2];
  if (p == 3) r = P.B[3];
  if (p == 4) r = P.B[4];
  if (p == 5) r = P.B[5];
  return r;
}

// stage one 16KB half (256 rows x 32 bf16) into LDS slot; linear LDS dest,
// inverse-swizzled global source (rule #21). 2 x global_load_lds per thread.
__device__ __forceinline__ void stage_half(const unsigned short* base, int rowoff,
                                           int ktp, int kk, int slot,
                                           int wid, int lane, unsigned char* smem) {
#pragma unroll
  for (int i = 0; i < 2; ++i) {
    int row = wid * 32 + i * 16 + (lane >> 2);
    int kcol8 = (lane & 3) ^ ((row >> 1) & 3);
    const unsigned short* src = base + (size_t)(rowoff + row) * 1024
                                + ktp * 64 + kk * 32 + kcol8 * 8;
    unsigned int doff = (unsigned int)(slot * 16384 + wid * 2048 + i * 1024);
    __builtin_amdgcn_global_load_lds(
        (const __attribute__((address_space(1))) void*)src,
        (__attribute__((address_space(3))) void*)(smem + doff), 16, 0, 0);
  }
}

__device__ __forceinline__ short8 frag_ld(const unsigned char* smem, int slot, int row, int kg) {
  int byte = slot * 16384 + row * 64 + ((kg ^ ((row >> 1) & 3)) * 16);
  return *reinterpret_cast<const short8*>(smem + byte);
}

__global__ __launch_bounds__(512, 2) void gemm256_kernel(GemmPasses P, void* __restrict__ Cout,
                                                         int N, int NT,
                                                         const float* __restrict__ bias,
                                                         int omode) {
  __shared__ __attribute__((aligned(16))) unsigned char smem[131072];
  const int tid = threadIdx.x;
  const int wid = tid >> 6;
  const int lane = tid & 63;
  const int wm = wid >> 2;
  const int wn = wid & 3;
  const int frow = lane & 15;
  const int kg = lane >> 4;
  // T1: bijective XCD swizzle (nwg % 8 == 0 for all launches here)
  const int nwg = gridDim.x * gridDim.y;
  const int wg = blockIdx.y * gridDim.x + blockIdx.x;
  const int swz = (wg & 7) * (nwg >> 3) + (wg >> 3);
  const int brow = (swz / gridDim.x) << 8;
  const int bcol = (swz % gridDim.x) << 8;

  f32x4 acc[8][4];
#pragma unroll
  for (int f = 0; f < 8; ++f)
#pragma unroll
    for (int c = 0; c < 4; ++c)
      acc[f][c] = (f32x4){0.f, 0.f, 0.f, 0.f};

  // prologue: stage halves 0..6 (tile0 complete + tile1 A-k0,B-k0,A-k1)
  stage_half(selA(P, 0), brow, 0, 0, 0, wid, lane, smem);
  stage_half(selB(P, 0), bcol, 0, 0, 1, wid, lane, smem);
  stage_half(selA(P, 0), brow, 0, 1, 2, wid, lane, smem);
  stage_half(selB(P, 0), bcol, 0, 1, 3, wid, lane, smem);
  stage_half(selA(P, 0), brow, 1, 0, 4, wid, lane, smem);
  stage_half(selB(P, 0), bcol, 1, 0, 5, wid, lane, smem);
  stage_half(selA(P, 0), brow, 1, 1, 6, wid, lane, smem);
  WAIT_VM6();
  GBAR();

  for (int t = 0; t < NT; ++t) {
    const int cur4 = (t & 1) * 4;
    const int nxt4 = cur4 ^ 4;
    short8 a[4], b[4];
    // ---- phase 0: read A-k0 rows0-3 + B-k0; stage B-k1 of tile t+1 ----
#pragma unroll
    for (int f = 0; f < 4; ++f) a[f] = frag_ld(smem, cur4 + 0, wm * 128 + f * 16 + frow, kg);
#pragma unroll
    for (int c = 0; c < 4; ++c) b[c] = frag_ld(smem, cur4 + 1, wn * 64 + c * 16 + frow, kg);
    if (t + 1 < NT) {
      int ts = t + 1;
      stage_half(selB(P, ts >> 4), bcol, ts & 15, 1, nxt4 + 3, wid, lane, smem);
    }
    GBAR();
    __builtin_amdgcn_s_setprio(1);
#pragma unroll
    for (int f = 0; f < 4; ++f)
#pragma unroll
      for (int c = 0; c < 4; ++c)
        acc[f][c] = __builtin_amdgcn_mfma_f32_16x16x32_bf16(a[f], b[c], acc[f][c], 0, 0, 0);
    __builtin_amdgcn_s_setprio(0);
    GBAR();
    // ---- phase 1: read A-k0 rows4-7; stage A-k0 of tile t+2 ----
#pragma unroll
    for (int f = 0; f < 4; ++f) a[f] = frag_ld(smem, cur4 + 0, wm * 128 + (f + 4) * 16 + frow, kg);
    if (t + 2 < NT) {
      int ts = t + 2;
      stage_half(selA(P, ts >> 4), brow, ts & 15, 0, cur4 + 0, wid, lane, smem);
    }
    GBAR();
    __builtin_amdgcn_s_setprio(1);
#pragma unroll
    for (int f = 0; f < 4; ++f)
#pragma unroll
      for (int c = 0; c < 4; ++c)
        acc[f + 4][c] = __builtin_amdgcn_mfma_f32_16x16x32_bf16(a[f], b[c], acc[f + 4][c], 0, 0, 0);
    __builtin_amdgcn_s_setprio(0);
    GBAR();
    // ---- phase 2: read A-k1 rows0-3 + B-k1; stage B-k0 of tile t+2 ----
#pragma unroll
    for (int f = 0; f < 4; ++f) a[f] = frag_ld(smem, cur4 + 2, wm * 128 + f * 16 + frow, kg);
#pragma unroll
    for (int c = 0; c < 4; ++c) b[c] = frag_ld(smem, cur4 + 3, wn * 64 + c * 16 + frow, kg);
    if (t + 2 < NT) {
      int ts = t + 2;
      stage_half(selB(P, ts >> 4), bcol, ts & 15, 0, cur4 + 1, wid, lane, smem);
    }
    GBAR();
    __builtin_amdgcn_s_setprio(1);
#pragma unroll
    for (int f = 0; f < 4; ++f)
#pragma unroll
      for (int c = 0; c < 4; ++c)
        acc[f][c] = __builtin_amdgcn_mfma_f32_16x16x32_bf16(a[f], b[c], acc[f][c], 0, 0, 0);
    __builtin_amdgcn_s_setprio(0);
    GBAR();
    // ---- phase 3: read A-k1 rows4-7; stage A-k1 of tile t+2; vmcnt(6) ----
#pragma unroll
    for (int f = 0; f < 4; ++f) a[f] = frag_ld(smem, cur4 + 2, wm * 128 + (f + 4) * 16 + frow, kg);
    if (t + 2 < NT) {
      int ts = t + 2;
      stage_half(selA(P, ts >> 4), brow, ts & 15, 1, cur4 + 2, wid, lane, smem);
    }
    WAIT_VM6();
    GBAR();
    __builtin_amdgcn_s_setprio(1);
#pragma unroll
    for (int f = 0; f < 4; ++f)
#pragma unroll
      for (int c = 0; c < 4; ++c)
        acc[f + 4][c] = __builtin_amdgcn_mfma_f32_16x16x32_bf16(a[f], b[c], acc[f + 4][c], 0, 0, 0);
    __builtin_amdgcn_s_setprio(0);
    GBAR();
  }
  WAIT_VM0();

  // epilogue: C/D layout col=lane&15, row=(lane>>4)*4+q
#pragma unroll
  for (int f = 0; f < 8; ++f) {
    int r0 = brow + wm * 128 + f * 16 + kg * 4;
#pragma unroll
    for (int c = 0; c < 4; ++c) {
      int cc = bcol + wn * 64 + c * 16 + frow;
      if (omode == 0) {
        float bb = bias ? bias[cc] : 0.f;
        float* C = (float*)Cout;
#pragma unroll
        for (int q = 0; q < 4; ++q)
          C[(size_t)(r0 + q) * N + cc] = acc[f][c][q] + bb;
      } else {
        unsigned short* C = (unsigned short*)Cout;
#pragma unroll
        for (int q = 0; q < 4; ++q)
          C[(size_t)(r0 + q) * N + cc] = f2bf(acc[f][c][q]);
      }
    }
  }
}

// ---------------- WKV scan (fp64 state), windowed chunks over T ----------------
__global__ void wkv_scan_kernel(const float* __restrict__ kbuf,
                                const float* __restrict__ vbuf,
                                const unsigned short* __restrict__ rbuf,
                                const float* __restrict__ tdec,
                                unsigned short* __restrict__ rw1,
                                unsigned short* __restrict__ rw2) {
  const int h = blockIdx.x * 64 + threadIdx.x;
  const int chunk = blockIdx.y;
  const int b = blockIdx.z;
  const int t0 = chunk * SCAN_C;
  const int tstart = (chunk == 0) ? 0 : (t0 - SCAN_W);
  const int tend = t0 + SCAN_C;
  double num, den;
  if (chunk == 0) { num = 1.0; den = 1.0; } else { num = 0.0; den = 0.0; }
  const double w = (double)tdec[h];
  size_t idx = ((size_t)b * T_DIM + tstart) * H_DIM + h;
  float kc = kbuf[idx];
  float vc = vbuf[idx];
  unsigned short rc = rbuf[idx];
  for (int t = tstart; t < tend; ++t) {
    size_t idxn = idx + ((t + 1 < tend) ? H_DIM : 0);
    float kn = kbuf[idxn];
    float vn = vbuf[idxn];
    unsigned short rn = rbuf[idxn];
    double ck = (double)kc;
    if (t >= t0) {
      double p = w * ck;
      double A = fma(p, den, num);
      double Bd = den + p;
      float outf = (float)A / (float)Bd;
      float rr = 1.0f / (1.0f + __expf(-bf2f(rc)));
      float rw = rr * outf;
      unsigned short h1 = f2bf(rw);
      rw1[idx] = h1;
      rw2[idx] = f2bf(rw - bf2f(h1));
    }
    double ek = fast_exp64(ck);
    num = fma(w, num, ek * (double)vc);
    den = fma(w, den, ek);
    kc = kn; vc = vn; rc = rn;
    idx += H_DIM;
  }
}

// -------------------------------- host --------------------------------
static inline void run_gemm(const GemmPasses& P, void* C, int Mrows, int N,
                            const float* bias, int omode, hipStream_t stream) {
  gemm256_kernel<<<dim3(N / 256, Mrows / 256), dim3(512), 0, stream>>>(
      P, C, N, P.n * 16, bias, omode);
}

extern "C" void kernel_launch(void* const* d_in, const int* in_sizes, int n_in,
                              void* d_out, int out_size, void* d_ws, size_t ws_size,
                              hipStream_t stream) {
  const float* x    = (const float*)d_in[0];
  const float* tdec = (const float*)d_in[1];
  const float* tmk  = (const float*)d_in[2];
  const float* tmv  = (const float*)d_in[3];
  const float* tmr  = (const float*)d_in[4];
  const float* Wrec = (const float*)d_in[5];
  const float* Wkey = (const float*)d_in[6];
  const float* Wval = (const float*)d_in[7];
  const float* Wout = (const float*)d_in[8];
  const float* bout = (const float*)d_in[9];
  float* out = (float*)d_out;
  unsigned char* ws = (unsigned char*)d_ws;

  const size_t W2 = (size_t)H_DIM * H_DIM * 2;
  const size_t BF_FULL = (size_t)M_DIM * H_DIM * 2;
  const size_t F_FULL  = (size_t)M_DIM * H_DIM * 4;
  const size_t BF_B = BF_FULL / B_DIM;
  const size_t F_B  = F_FULL / B_DIM;

  const size_t NEED_A = 3 * BF_FULL + F_FULL + BF_FULL + 9 * W2;  // 210MB
  const size_t NEED_B = 3 * BF_B + F_B + BF_B + 9 * W2;           // 66MB
  const size_t NEED_C = NEED_B - BF_B;                            // 58MB

  int plan;
  size_t szXS, szV, szR;
  if (ws_size >= NEED_A)      { plan = 0; szXS = BF_FULL; szV = F_FULL; szR = BF_FULL; }
  else if (ws_size >= NEED_B) { plan = 1; szXS = BF_B; szV = F_B; szR = BF_B; }
  else if (ws_size >= NEED_C) { plan = 2; szXS = BF_B; szV = F_B; szR = BF_B; }
  else return;
  const int has3 = (plan != 2);

  size_t off = 0;
  unsigned short* XS1 = (unsigned short*)(ws + off); off += szXS;
  unsigned short* XS2 = (unsigned short*)(ws + off); off += szXS;
  unsigned short* XS3 = (unsigned short*)(ws + off); if (has3) off += szXS;
  float*          V   = (float*)(ws + off);          off += szV;
  unsigned short* R   = (unsigned short*)(ws + off); off += szR;
  unsigned short* WV1 = (unsigned short*)(ws + off); off += W2;
  unsigned short* WV2 = (unsigned short*)(ws + off); off += W2;
  unsigned short* WR1 = (unsigned short*)(ws + off); off += W2;
  unsigned short* WR2 = (unsigned short*)(ws + off); off += W2;
  unsigned short* WK1 = (unsigned short*)(ws + off); off += W2;
  unsigned short* WK2 = (unsigned short*)(ws + off); off += W2;
  unsigned short* WK3 = (unsigned short*)(ws + off); off += W2;
  unsigned short* WO1 = (unsigned short*)(ws + off); off += W2;
  unsigned short* WO2 = (unsigned short*)(ws + off); off += W2;

  wprep_kernel<<<dim3(H_DIM * H_DIM / 256), dim3(256), 0, stream>>>(
      Wrec, Wkey, Wval, Wout, tmk, tmv, tmr, WV1, WV2, WR1, WR2, WK1, WK2, WK3, WO1, WO2);

  // pass lists ordered small -> large magnitude (accumulator rounding control)
  GemmPasses Pv, Pr, Pk, Po;
  Pv.A[0]=XS1; Pv.B[0]=WV2;  Pv.A[1]=XS2; Pv.B[1]=WV1;  Pv.A[2]=XS1; Pv.B[2]=WV1;
  Pv.A[3]=XS1; Pv.B[3]=WV1;  Pv.A[4]=XS1; Pv.B[4]=WV1;  Pv.A[5]=XS1; Pv.B[5]=WV1;  Pv.n=3;
  Pr.A[0]=XS1; Pr.B[0]=WR2;  Pr.A[1]=XS2; Pr.B[1]=WR1;  Pr.A[2]=XS1; Pr.B[2]=WR1;
  Pr.A[3]=XS1; Pr.B[3]=WR1;  Pr.A[4]=XS1; Pr.B[4]=WR1;  Pr.A[5]=XS1; Pr.B[5]=WR1;  Pr.n=3;
  if (has3) {
    Pk.A[0]=XS2; Pk.B[0]=WK2;  Pk.A[1]=XS1; Pk.B[1]=WK3;  Pk.A[2]=XS3; Pk.B[2]=WK1;
    Pk.A[3]=XS1; Pk.B[3]=WK2;  Pk.A[4]=XS2; Pk.B[4]=WK1;  Pk.A[5]=XS1; Pk.B[5]=WK1;
    Pk.n = 6;
  } else {
    Pk.A[0]=XS2; Pk.B[0]=WK2;  Pk.A[1]=XS1; Pk.B[1]=WK3;  Pk.A[2]=XS1; Pk.B[2]=WK2;
    Pk.A[3]=XS2; Pk.B[3]=WK1;  Pk.A[4]=XS1; Pk.B[4]=WK1;  Pk.A[5]=XS1; Pk.B[5]=WK1;
    Pk.n = 5;
  }
  Po.A[0]=XS1; Po.B[0]=WO2;  Po.A[1]=XS2; Po.B[1]=WO1;  Po.A[2]=XS1; Po.B[2]=WO1;
  Po.A[3]=XS1; Po.B[3]=WO1;  Po.A[4]=XS1; Po.B[4]=WO1;  Po.A[5]=XS1; Po.B[5]=WO1;  Po.n=3;

  if (plan == 0) {
    int n4 = M_DIM * (H_DIM / 4);
    xs_split_kernel<<<dim3(n4 / 256), dim3(256), 0, stream>>>(x, XS1, XS2, XS3, n4, 1);
    run_gemm(Pv, V,   M_DIM, H_DIM, nullptr, 0, stream);
    run_gemm(Pr, R,   M_DIM, H_DIM, nullptr, 1, stream);
    run_gemm(Pk, out, M_DIM, H_DIM, nullptr, 0, stream);
    wkv_scan_kernel<<<dim3(H_DIM / 64, T_DIM / SCAN_C, B_DIM), dim3(64), 0, stream>>>(
        out, V, R, tdec, XS1, XS2);
    run_gemm(Po, out, M_DIM, H_DIM, bout, 0, stream);
  } else {
    for (int b = 0; b < B_DIM; ++b) {
      const float* xb = x + (size_t)b * T_DIM * H_DIM;
      float* kb = out + (size_t)b * T_DIM * H_DIM;
      int n4 = T_DIM * (H_DIM / 4);
      xs_split_kernel<<<dim3(n4 / 256), dim3(256), 0, stream>>>(xb, XS1, XS2, XS3, n4, has3);
      run_gemm(Pv, V,  T_DIM, H_DIM, nullptr, 0, stream);
      run_gemm(Pr, R,  T_DIM, H_DIM, nullptr, 1, stream);
      run_gemm(Pk, kb, T_DIM, H_DIM, nullptr, 0, stream);
      wkv_scan_kernel<<<dim3(H_DIM / 64, T_DIM / SCAN_C, 1), dim3(64), 0, stream>>>(
          kb, V, R, tdec, XS1, XS2);
      run_gemm(Po, kb, T_DIM, H_DIM, bout, 0, stream);
    }
  }
}

// Round 5
// 483.926 us; speedup vs baseline: 2.6188x; 1.4156x over previous
//
#include <hip/hip_runtime.h>

#define H_DIM 1024
#define T_DIM 4096
#define B_DIM 4
#define M_DIM (B_DIM * T_DIM)   // 16384
#define SCAN_C 128
#define SCAN_W 96

typedef __attribute__((ext_vector_type(8))) short short8;
typedef __attribute__((ext_vector_type(4))) float f32x4;
typedef _Float16 half8 __attribute__((ext_vector_type(8)));

__device__ __forceinline__ unsigned short f2bf(float f) {
  unsigned int b = __float_as_uint(f);
  return (unsigned short)((b + 0x7FFFu + ((b >> 16) & 1u)) >> 16);
}
__device__ __forceinline__ float bf2f(unsigned short u) {
  return __uint_as_float(((unsigned int)u) << 16);
}
__device__ __forceinline__ unsigned short f2h(float f) {
  _Float16 h = (_Float16)f;
  return __builtin_bit_cast(unsigned short, h);
}

__device__ __forceinline__ double fast_exp64(double x) {
  const double L2E = 1.4426950408889634074;
  const double LN2 = 0.69314718055994530942;
  double z = x * L2E;
  double n = rint(z);
  double y = (z - n) * LN2;
  double p = 2.7557319223985890653e-6;
  p = fma(p, y, 2.4801587301587301566e-5);
  p = fma(p, y, 1.9841269841269841253e-4);
  p = fma(p, y, 1.3888888888888889419e-3);
  p = fma(p, y, 8.3333333333333332177e-3);
  p = fma(p, y, 4.1666666666666664354e-2);
  p = fma(p, y, 1.6666666666666665741e-1);
  p = fma(p, y, 0.5);
  p = fma(p, y, 1.0);
  p = fma(p, y, 1.0);
  long long bits = ((long long)(1023 + (int)n)) << 52;
  return p * __longlong_as_double(bits);
}

// ------- xs = x + time_shift(x); bf16 triple split (for k) + fp16 copy (for v,r) -------
__global__ void xs_split_kernel(const float* __restrict__ x,
                                unsigned short* __restrict__ xs1,
                                unsigned short* __restrict__ xs2,
                                unsigned short* __restrict__ xs3,
                                unsigned short* __restrict__ xsh,
                                int n4, int has3) {
  int i = blockIdx.x * blockDim.x + threadIdx.x;
  const int HV = H_DIM / 4;
  if (i >= n4) return;
  int m = i / HV;
  int t = m & (T_DIM - 1);
  float4 cur = reinterpret_cast<const float4*>(x)[i];
  float4 prev = make_float4(0.f, 0.f, 0.f, 0.f);
  if (t > 0) prev = reinterpret_cast<const float4*>(x)[i - HV];
  float s[4] = {cur.x + prev.x, cur.y + prev.y, cur.z + prev.z, cur.w + prev.w};
  unsigned short a1[4], a2[4], a3[4], ah[4];
#pragma unroll
  for (int q = 0; q < 4; ++q) {
    float v = s[q];
    unsigned short h1 = f2bf(v);
    float f1 = bf2f(h1);
    unsigned short h2 = f2bf(v - f1);
    a1[q] = h1; a2[q] = h2;
    a3[q] = f2bf(v - f1 - bf2f(h2));
    ah[q] = f2h(v);
  }
  reinterpret_cast<ushort4*>(xs1)[i] = make_ushort4(a1[0], a1[1], a1[2], a1[3]);
  reinterpret_cast<ushort4*>(xs2)[i] = make_ushort4(a2[0], a2[1], a2[2], a2[3]);
  if (has3)
    reinterpret_cast<ushort4*>(xs3)[i] = make_ushort4(a3[0], a3[1], a3[2], a3[3]);
  reinterpret_cast<ushort4*>(xsh)[i] = make_ushort4(ah[0], ah[1], ah[2], ah[3]);
}

// ------------- weight prep: k = bf16 triple split; v,r,out = fp16 single -------------
__global__ void wprep_kernel(const float* __restrict__ Wrec, const float* __restrict__ Wkey,
                             const float* __restrict__ Wval, const float* __restrict__ Wout,
                             const float* __restrict__ tmk, const float* __restrict__ tmv,
                             const float* __restrict__ tmr,
                             unsigned short* __restrict__ WVH, unsigned short* __restrict__ WRH,
                             unsigned short* __restrict__ WK1, unsigned short* __restrict__ WK2,
                             unsigned short* __restrict__ WK3,
                             unsigned short* __restrict__ WOH) {
  int i = blockIdx.x * blockDim.x + threadIdx.x;
  if (i >= H_DIM * H_DIM) return;
  int j = i & (H_DIM - 1);
  float wk = Wkey[i] * tmk[j];
  unsigned short k1 = f2bf(wk); float kf1 = bf2f(k1);
  unsigned short k2 = f2bf(wk - kf1); float kf2 = bf2f(k2);
  WK1[i] = k1; WK2[i] = k2; WK3[i] = f2bf(wk - kf1 - kf2);
  WVH[i] = f2h(Wval[i] * tmv[j]);
  WRH[i] = f2h(Wrec[i] * tmr[j]);
  WOH[i] = f2h(Wout[i]);
}

// =================== 256x256 8-phase multi-pass GEMM (bf16 or fp16) ===================
// C = sum_p A_p @ B_p^T.  A_p [M,1024], B_p [N,1024] row-major, 2-byte elems.
// 8 waves (2Mx4N), BK=64, LDS 128KB = 8 half-slots, stage-lead 7 halves,
// vmcnt(6) per K-tile (T3+T4), swizzled LDS (T2), setprio (T5), XCD swizzle (T1).
struct GemmPasses {
  const unsigned short* A[6];
  const unsigned short* B[6];
  int n;
};

#define GBAR() do { asm volatile("" ::: "memory"); __builtin_amdgcn_sched_barrier(0); \
                    __builtin_amdgcn_s_barrier(); \
                    __builtin_amdgcn_sched_barrier(0); asm volatile("" ::: "memory"); } while (0)
#define WAIT_VM6() asm volatile("s_waitcnt vmcnt(6)" ::: "memory")
#define WAIT_VM0() asm volatile("s_waitcnt vmcnt(0)" ::: "memory")

template <int DT>
__device__ __forceinline__ f32x4 mma(short8 a, short8 b, f32x4 c) {
  if constexpr (DT == 0)
    return __builtin_amdgcn_mfma_f32_16x16x32_bf16(a, b, c, 0, 0, 0);
  else
    return __builtin_amdgcn_mfma_f32_16x16x32_f16(
        __builtin_bit_cast(half8, a), __builtin_bit_cast(half8, b), c, 0, 0, 0);
}

__device__ __forceinline__ const unsigned short* selA(const GemmPasses& P, int p) {
  const unsigned short* r = P.A[0];
  if (p == 1) r = P.A[1];
  if (p == 2) r = P.A[2];
  if (p == 3) r = P.A[3];
  if (p == 4) r = P.A[4];
  if (p == 5) r = P.A[5];
  return r;
}
__device__ __forceinline__ const unsigned short* selB(const GemmPasses& P, int p) {
  const unsigned short* r = P.B[0];
  if (p == 1) r = P.B[1];
  if (p == 2) r = P.B[2];
  if (p == 3) r = P.B[3];
  if (p == 4) r = P.B[4];
  if (p == 5) r = P.B[5];
  return r;
}

// stage one 16KB half (256 rows x 32 elems) into LDS slot; linear LDS dest,
// inverse-swizzled global source (rule #21). 2 x global_load_lds per thread.
__device__ __forceinline__ void stage_half(const unsigned short* base, int rowoff,
                                           int ktp, int kk, int slot,
                                           int wid, int lane, unsigned char* smem) {
#pragma unroll
  for (int i = 0; i < 2; ++i) {
    int row = wid * 32 + i * 16 + (lane >> 2);
    int kcol8 = (lane & 3) ^ ((row >> 1) & 3);
    const unsigned short* src = base + (size_t)(rowoff + row) * 1024
                                + ktp * 64 + kk * 32 + kcol8 * 8;
    unsigned int doff = (unsigned int)(slot * 16384 + wid * 2048 + i * 1024);
    __builtin_amdgcn_global_load_lds(
        (const __attribute__((address_space(1))) void*)src,
        (__attribute__((address_space(3))) void*)(smem + doff), 16, 0, 0);
  }
}

__device__ __forceinline__ short8 frag_ld(const unsigned char* smem, int slot, int row, int kg) {
  int byte = slot * 16384 + row * 64 + ((kg ^ ((row >> 1) & 3)) * 16);
  return *reinterpret_cast<const short8*>(smem + byte);
}

template <int DT>
__global__ __launch_bounds__(512, 2) void gemm256_kernel(GemmPasses P, void* __restrict__ Cout,
                                                         int N, int NT,
                                                         const float* __restrict__ bias,
                                                         int omode) {
  __shared__ __attribute__((aligned(16))) unsigned char smem[131072];
  const int tid = threadIdx.x;
  const int wid = tid >> 6;
  const int lane = tid & 63;
  const int wm = wid >> 2;
  const int wn = wid & 3;
  const int frow = lane & 15;
  const int kg = lane >> 4;
  const int nwg = gridDim.x * gridDim.y;
  const int wg = blockIdx.y * gridDim.x + blockIdx.x;
  const int swz = (wg & 7) * (nwg >> 3) + (wg >> 3);
  const int brow = (swz / gridDim.x) << 8;
  const int bcol = (swz % gridDim.x) << 8;

  f32x4 acc[8][4];
#pragma unroll
  for (int f = 0; f < 8; ++f)
#pragma unroll
    for (int c = 0; c < 4; ++c)
      acc[f][c] = (f32x4){0.f, 0.f, 0.f, 0.f};

  // prologue: stage halves of tile0 (4) + tile1 A-k0,B-k0,A-k1 (3)
  stage_half(selA(P, 0), brow, 0, 0, 0, wid, lane, smem);
  stage_half(selB(P, 0), bcol, 0, 0, 1, wid, lane, smem);
  stage_half(selA(P, 0), brow, 0, 1, 2, wid, lane, smem);
  stage_half(selB(P, 0), bcol, 0, 1, 3, wid, lane, smem);
  stage_half(selA(P, 0), brow, 1, 0, 4, wid, lane, smem);
  stage_half(selB(P, 0), bcol, 1, 0, 5, wid, lane, smem);
  stage_half(selA(P, 0), brow, 1, 1, 6, wid, lane, smem);
  WAIT_VM6();
  GBAR();

  for (int t = 0; t < NT; ++t) {
    const int cur4 = (t & 1) * 4;
    const int nxt4 = cur4 ^ 4;
    short8 a[4], b[4];
    // ---- phase 0: read A-k0 rows0-3 + B-k0; stage B-k1 of tile t+1 ----
#pragma unroll
    for (int f = 0; f < 4; ++f) a[f] = frag_ld(smem, cur4 + 0, wm * 128 + f * 16 + frow, kg);
#pragma unroll
    for (int c = 0; c < 4; ++c) b[c] = frag_ld(smem, cur4 + 1, wn * 64 + c * 16 + frow, kg);
    if (t + 1 < NT) {
      int ts = t + 1;
      stage_half(selB(P, ts >> 4), bcol, ts & 15, 1, nxt4 + 3, wid, lane, smem);
    }
    GBAR();
    __builtin_amdgcn_s_setprio(1);
#pragma unroll
    for (int f = 0; f < 4; ++f)
#pragma unroll
      for (int c = 0; c < 4; ++c)
        acc[f][c] = mma<DT>(a[f], b[c], acc[f][c]);
    __builtin_amdgcn_s_setprio(0);
    GBAR();
    // ---- phase 1: read A-k0 rows4-7; stage A-k0 of tile t+2 ----
#pragma unroll
    for (int f = 0; f < 4; ++f) a[f] = frag_ld(smem, cur4 + 0, wm * 128 + (f + 4) * 16 + frow, kg);
    if (t + 2 < NT) {
      int ts = t + 2;
      stage_half(selA(P, ts >> 4), brow, ts & 15, 0, cur4 + 0, wid, lane, smem);
    }
    GBAR();
    __builtin_amdgcn_s_setprio(1);
#pragma unroll
    for (int f = 0; f < 4; ++f)
#pragma unroll
      for (int c = 0; c < 4; ++c)
        acc[f + 4][c] = mma<DT>(a[f], b[c], acc[f + 4][c]);
    __builtin_amdgcn_s_setprio(0);
    GBAR();
    // ---- phase 2: read A-k1 rows0-3 + B-k1; stage B-k0 of tile t+2 ----
#pragma unroll
    for (int f = 0; f < 4; ++f) a[f] = frag_ld(smem, cur4 + 2, wm * 128 + f * 16 + frow, kg);
#pragma unroll
    for (int c = 0; c < 4; ++c) b[c] = frag_ld(smem, cur4 + 3, wn * 64 + c * 16 + frow, kg);
    if (t + 2 < NT) {
      int ts = t + 2;
      stage_half(selB(P, ts >> 4), bcol, ts & 15, 0, cur4 + 1, wid, lane, smem);
    }
    GBAR();
    __builtin_amdgcn_s_setprio(1);
#pragma unroll
    for (int f = 0; f < 4; ++f)
#pragma unroll
      for (int c = 0; c < 4; ++c)
        acc[f][c] = mma<DT>(a[f], b[c], acc[f][c]);
    __builtin_amdgcn_s_setprio(0);
    GBAR();
    // ---- phase 3: read A-k1 rows4-7; stage A-k1 of tile t+2; vmcnt(6) ----
#pragma unroll
    for (int f = 0; f < 4; ++f) a[f] = frag_ld(smem, cur4 + 2, wm * 128 + (f + 4) * 16 + frow, kg);
    if (t + 2 < NT) {
      int ts = t + 2;
      stage_half(selA(P, ts >> 4), brow, ts & 15, 1, cur4 + 2, wid, lane, smem);
    }
    WAIT_VM6();
    GBAR();
    __builtin_amdgcn_s_setprio(1);
#pragma unroll
    for (int f = 0; f < 4; ++f)
#pragma unroll
      for (int c = 0; c < 4; ++c)
        acc[f + 4][c] = mma<DT>(a[f], b[c], acc[f + 4][c]);
    __builtin_amdgcn_s_setprio(0);
    GBAR();
  }
  WAIT_VM0();

  // epilogue: C/D layout col=lane&15, row=(lane>>4)*4+q
#pragma unroll
  for (int f = 0; f < 8; ++f) {
    int r0 = brow + wm * 128 + f * 16 + kg * 4;
#pragma unroll
    for (int c = 0; c < 4; ++c) {
      int cc = bcol + wn * 64 + c * 16 + frow;
      if (omode == 0) {
        float bb = bias ? bias[cc] : 0.f;
        float* C = (float*)Cout;
#pragma unroll
        for (int q = 0; q < 4; ++q)
          C[(size_t)(r0 + q) * N + cc] = acc[f][c][q] + bb;
      } else {
        unsigned short* C = (unsigned short*)Cout;
#pragma unroll
        for (int q = 0; q < 4; ++q)
          C[(size_t)(r0 + q) * N + cc] = f2bf(acc[f][c][q]);
      }
    }
  }
}

// ---------------- WKV scan (fp64 state), windowed chunks over T ----------------
// outputs rw = sigmoid(r)*wkv as a single fp16 value (feeds fp16 out-projection)
__global__ void wkv_scan_kernel(const float* __restrict__ kbuf,
                                const float* __restrict__ vbuf,
                                const unsigned short* __restrict__ rbuf,
                                const float* __restrict__ tdec,
                                unsigned short* __restrict__ rwh) {
  const int h = blockIdx.x * 64 + threadIdx.x;
  const int chunk = blockIdx.y;
  const int b = blockIdx.z;
  const int t0 = chunk * SCAN_C;
  const int tstart = (chunk == 0) ? 0 : (t0 - SCAN_W);
  const int tend = t0 + SCAN_C;
  double num, den;
  if (chunk == 0) { num = 1.0; den = 1.0; } else { num = 0.0; den = 0.0; }
  const double w = (double)tdec[h];
  size_t idx = ((size_t)b * T_DIM + tstart) * H_DIM + h;
  float kc = kbuf[idx];
  float vc = vbuf[idx];
  unsigned short rc = rbuf[idx];
  for (int t = tstart; t < tend; ++t) {
    size_t idxn = idx + ((t + 1 < tend) ? H_DIM : 0);
    float kn = kbuf[idxn];
    float vn = vbuf[idxn];
    unsigned short rn = rbuf[idxn];
    double ck = (double)kc;
    if (t >= t0) {
      double p = w * ck;
      double A = fma(p, den, num);
      double Bd = den + p;
      float outf = (float)A / (float)Bd;
      float rr = 1.0f / (1.0f + __expf(-bf2f(rc)));
      rwh[idx] = f2h(rr * outf);
    }
    double ek = fast_exp64(ck);
    num = fma(w, num, ek * (double)vc);
    den = fma(w, den, ek);
    kc = kn; vc = vn; rc = rn;
    idx += H_DIM;
  }
}

// -------------------------------- host --------------------------------
template <int DT>
static inline void run_gemm(const GemmPasses& P, void* C, int Mrows, int N,
                            const float* bias, int omode, hipStream_t stream) {
  gemm256_kernel<DT><<<dim3(N / 256, Mrows / 256), dim3(512), 0, stream>>>(
      P, C, N, P.n * 16, bias, omode);
}

extern "C" void kernel_launch(void* const* d_in, const int* in_sizes, int n_in,
                              void* d_out, int out_size, void* d_ws, size_t ws_size,
                              hipStream_t stream) {
  const float* x    = (const float*)d_in[0];
  const float* tdec = (const float*)d_in[1];
  const float* tmk  = (const float*)d_in[2];
  const float* tmv  = (const float*)d_in[3];
  const float* tmr  = (const float*)d_in[4];
  const float* Wrec = (const float*)d_in[5];
  const float* Wkey = (const float*)d_in[6];
  const float* Wval = (const float*)d_in[7];
  const float* Wout = (const float*)d_in[8];
  const float* bout = (const float*)d_in[9];
  float* out = (float*)d_out;
  unsigned char* ws = (unsigned char*)d_ws;

  const size_t W2 = (size_t)H_DIM * H_DIM * 2;
  const size_t BF_FULL = (size_t)M_DIM * H_DIM * 2;
  const size_t F_FULL  = (size_t)M_DIM * H_DIM * 4;
  const size_t BF_B = BF_FULL / B_DIM;
  const size_t F_B  = F_FULL / B_DIM;

  const size_t NEED_A = 3 * BF_FULL + F_FULL + BF_FULL + 6 * W2;  // 204MB
  const size_t NEED_B = 3 * BF_B + F_B + BF_B + 6 * W2;           // 60MB
  const size_t NEED_C = NEED_B - BF_B;                            // 52MB

  int plan;
  size_t szXS, szV, szR;
  if (ws_size >= NEED_A)      { plan = 0; szXS = BF_FULL; szV = F_FULL; szR = BF_FULL; }
  else if (ws_size >= NEED_B) { plan = 1; szXS = BF_B; szV = F_B; szR = BF_B; }
  else if (ws_size >= NEED_C) { plan = 2; szXS = BF_B; szV = F_B; szR = BF_B; }
  else return;
  const int has3 = (plan != 2);

  size_t off = 0;
  unsigned short* XS1 = (unsigned short*)(ws + off); off += szXS;
  unsigned short* XS2 = (unsigned short*)(ws + off); off += szXS;
  unsigned short* XS3 = (unsigned short*)(ws + off); if (has3) off += szXS;
  float*          V   = (float*)(ws + off);          off += szV;
  unsigned short* R   = (unsigned short*)(ws + off); off += szR;
  unsigned short* WVH = (unsigned short*)(ws + off); off += W2;
  unsigned short* WRH = (unsigned short*)(ws + off); off += W2;
  unsigned short* WOH = (unsigned short*)(ws + off); off += W2;
  unsigned short* WK1 = (unsigned short*)(ws + off); off += W2;
  unsigned short* WK2 = (unsigned short*)(ws + off); off += W2;
  unsigned short* WK3 = (unsigned short*)(ws + off); off += W2;

  wprep_kernel<<<dim3(H_DIM * H_DIM / 256), dim3(256), 0, stream>>>(
      Wrec, Wkey, Wval, Wout, tmk, tmv, tmr, WVH, WRH, WK1, WK2, WK3, WOH);

  GemmPasses Pv, Pr, Pk, Po;
  Pv.n = 1;  Pr.n = 1;  Po.n = 1;
  // k: bf16 triple-split, small->large magnitude ordering (accumulator rounding)
  if (has3) {
    Pk.A[0]=XS2; Pk.B[0]=WK2;  Pk.A[1]=XS1; Pk.B[1]=WK3;  Pk.A[2]=XS3; Pk.B[2]=WK1;
    Pk.A[3]=XS1; Pk.B[3]=WK2;  Pk.A[4]=XS2; Pk.B[4]=WK1;  Pk.A[5]=XS1; Pk.B[5]=WK1;
    Pk.n = 6;
  } else {
    Pk.A[0]=XS2; Pk.B[0]=WK2;  Pk.A[1]=XS1; Pk.B[1]=WK3;  Pk.A[2]=XS1; Pk.B[2]=WK2;
    Pk.A[3]=XS2; Pk.B[3]=WK1;  Pk.A[4]=XS1; Pk.B[4]=WK1;  Pk.A[5]=XS1; Pk.B[5]=WK1;
    Pk.n = 5;
  }

  if (plan == 0) {
    // full-M pipeline; XSH (fp16 xs) lives in d_out, dead before Pk overwrites it;
    // rw (fp16) reuses XS1 after Pk.
    unsigned short* XSH = (unsigned short*)out;
    unsigned short* RWH = XS1;
    Pv.A[0]=XSH; Pv.B[0]=WVH;
    Pr.A[0]=XSH; Pr.B[0]=WRH;
    Po.A[0]=RWH; Po.B[0]=WOH;
    int n4 = M_DIM * (H_DIM / 4);
    xs_split_kernel<<<dim3(n4 / 256), dim3(256), 0, stream>>>(x, XS1, XS2, XS3, XSH, n4, 1);
    run_gemm<1>(Pv, V,   M_DIM, H_DIM, nullptr, 0, stream);
    run_gemm<1>(Pr, R,   M_DIM, H_DIM, nullptr, 1, stream);
    run_gemm<0>(Pk, out, M_DIM, H_DIM, nullptr, 0, stream);
    wkv_scan_kernel<<<dim3(H_DIM / 64, T_DIM / SCAN_C, B_DIM), dim3(64), 0, stream>>>(
        out, V, R, tdec, RWH);
    run_gemm<1>(Po, out, M_DIM, H_DIM, bout, 0, stream);
  } else {
    for (int b = 0; b < B_DIM; ++b) {
      const float* xb = x + (size_t)b * T_DIM * H_DIM;
      float* kb = out + (size_t)b * T_DIM * H_DIM;
      unsigned short* XSH = (unsigned short*)kb;
      unsigned short* RWH = XS1;
      Pv.A[0]=XSH; Pv.B[0]=WVH;
      Pr.A[0]=XSH; Pr.B[0]=WRH;
      Po.A[0]=RWH; Po.B[0]=WOH;
      int n4 = T_DIM * (H_DIM / 4);
      xs_split_kernel<<<dim3(n4 / 256), dim3(256), 0, stream>>>(xb, XS1, XS2, XS3, XSH, n4, has3);
      run_gemm<1>(Pv, V,  T_DIM, H_DIM, nullptr, 0, stream);
      run_gemm<1>(Pr, R,  T_DIM, H_DIM, nullptr, 1, stream);
      run_gemm<0>(Pk, kb, T_DIM, H_DIM, nullptr, 0, stream);
      wkv_scan_kernel<<<dim3(H_DIM / 64, T_DIM / SCAN_C, 1), dim3(64), 0, stream>>>(
          kb, V, R, tdec, RWH);
      run_gemm<1>(Po, kb, T_DIM, H_DIM, bout, 0, stream);
    }
  }
}

// Round 6
// 362.074 us; speedup vs baseline: 3.5002x; 1.3365x over previous
//
#include <hip/hip_runtime.h>

#define H_DIM 1024
#define T_DIM 4096
#define B_DIM 4
#define M_DIM (B_DIM * T_DIM)   // 16384
#define SCAN_C 64
#define SCAN_W 48

typedef __attribute__((ext_vector_type(8))) short short8;
typedef __attribute__((ext_vector_type(4))) float f32x4;
typedef _Float16 half8 __attribute__((ext_vector_type(8)));

__device__ __forceinline__ unsigned short f2h(float f) {
  _Float16 h = (_Float16)f;
  return __builtin_bit_cast(unsigned short, h);
}
__device__ __forceinline__ float h2f(unsigned short u) {
  return (float)__builtin_bit_cast(_Float16, u);
}

__device__ __forceinline__ double fast_exp64(double x) {
  const double L2E = 1.4426950408889634074;
  const double LN2 = 0.69314718055994530942;
  double z = x * L2E;
  double n = rint(z);
  double y = (z - n) * LN2;
  double p = 2.7557319223985890653e-6;
  p = fma(p, y, 2.4801587301587301566e-5);
  p = fma(p, y, 1.9841269841269841253e-4);
  p = fma(p, y, 1.3888888888888889419e-3);
  p = fma(p, y, 8.3333333333333332177e-3);
  p = fma(p, y, 4.1666666666666664354e-2);
  p = fma(p, y, 1.6666666666666665741e-1);
  p = fma(p, y, 0.5);
  p = fma(p, y, 1.0);
  p = fma(p, y, 1.0);
  long long bits = ((long long)(1023 + (int)n)) << 52;
  return p * __longlong_as_double(bits);
}

// ------- xs = x + time_shift(x); scaled fp16 double-split (x1 + x2*2^-11) -------
__global__ void xs_split_kernel(const float* __restrict__ x,
                                unsigned short* __restrict__ xs1,
                                unsigned short* __restrict__ xs2,
                                int n4) {
  int i = blockIdx.x * blockDim.x + threadIdx.x;
  const int HV = H_DIM / 4;
  if (i >= n4) return;
  int m = i / HV;
  int t = m & (T_DIM - 1);
  float4 cur = reinterpret_cast<const float4*>(x)[i];
  float4 prev = make_float4(0.f, 0.f, 0.f, 0.f);
  if (t > 0) prev = reinterpret_cast<const float4*>(x)[i - HV];
  float s[4] = {cur.x + prev.x, cur.y + prev.y, cur.z + prev.z, cur.w + prev.w};
  unsigned short a1[4], a2[4];
#pragma unroll
  for (int q = 0; q < 4; ++q) {
    unsigned short h1 = f2h(s[q]);
    a1[q] = h1;
    a2[q] = f2h((s[q] - h2f(h1)) * 2048.0f);
  }
  reinterpret_cast<ushort4*>(xs1)[i] = make_ushort4(a1[0], a1[1], a1[2], a1[3]);
  reinterpret_cast<ushort4*>(xs2)[i] = make_ushort4(a2[0], a2[1], a2[2], a2[3]);
}

// ------------- weight prep: k = scaled fp16 double-split; v,r,out fp16 -------------
__global__ void wprep_kernel(const float* __restrict__ Wrec, const float* __restrict__ Wkey,
                             const float* __restrict__ Wval, const float* __restrict__ Wout,
                             const float* __restrict__ tmk, const float* __restrict__ tmv,
                             const float* __restrict__ tmr,
                             unsigned short* __restrict__ WK1H, unsigned short* __restrict__ WK2H,
                             unsigned short* __restrict__ WVRH,
                             unsigned short* __restrict__ WOH) {
  int i = blockIdx.x * blockDim.x + threadIdx.x;
  if (i >= H_DIM * H_DIM) return;
  int j = i & (H_DIM - 1);
  float wk = Wkey[i] * tmk[j];
  unsigned short k1 = f2h(wk);
  WK1H[i] = k1;
  WK2H[i] = f2h((wk - h2f(k1)) * 2048.0f);
  WVRH[i] = f2h(Wval[i] * tmv[j]);                    // rows 0..1023: v-weights
  WVRH[H_DIM * H_DIM + i] = f2h(Wrec[i] * tmr[j]);   // rows 1024..2047: r-weights
  WOH[i] = f2h(Wout[i]);
}

// =================== 256x256 8-phase multi-pass fp16 GEMM ===================
// C = sum_p sc-folded A_p @ B_p^T (Horner: acc = acc*sc[p] before pass p).
// 8 waves (2Mx4N), BK=64, LDS 128KB = 8 half-slots, stage-lead 7 halves,
// vmcnt(6) per K-tile (T3+T4), swizzled LDS (T2), setprio (T5), XCD swizzle (T1).
struct GemmPasses {
  const unsigned short* A[6];
  const unsigned short* B[6];
  float sc[6];
  int n;
};

#define GBAR() do { asm volatile("" ::: "memory"); __builtin_amdgcn_sched_barrier(0); \
                    __builtin_amdgcn_s_barrier(); \
                    __builtin_amdgcn_sched_barrier(0); asm volatile("" ::: "memory"); } while (0)
#define WAIT_VM6() asm volatile("s_waitcnt vmcnt(6)" ::: "memory")
#define WAIT_VM0() asm volatile("s_waitcnt vmcnt(0)" ::: "memory")

template <int DT>
__device__ __forceinline__ f32x4 mma(short8 a, short8 b, f32x4 c) {
  if constexpr (DT == 0)
    return __builtin_amdgcn_mfma_f32_16x16x32_bf16(a, b, c, 0, 0, 0);
  else
    return __builtin_amdgcn_mfma_f32_16x16x32_f16(
        __builtin_bit_cast(half8, a), __builtin_bit_cast(half8, b), c, 0, 0, 0);
}

__device__ __forceinline__ const unsigned short* selA(const GemmPasses& P, int p) {
  const unsigned short* r = P.A[0];
  if (p == 1) r = P.A[1];
  if (p == 2) r = P.A[2];
  if (p == 3) r = P.A[3];
  if (p == 4) r = P.A[4];
  if (p == 5) r = P.A[5];
  return r;
}
__device__ __forceinline__ const unsigned short* selB(const GemmPasses& P, int p) {
  const unsigned short* r = P.B[0];
  if (p == 1) r = P.B[1];
  if (p == 2) r = P.B[2];
  if (p == 3) r = P.B[3];
  if (p == 4) r = P.B[4];
  if (p == 5) r = P.B[5];
  return r;
}

// stage one 16KB half (256 rows x 32 elems) into LDS slot; linear LDS dest,
// inverse-swizzled global source (rule #21). 2 x global_load_lds per thread.
__device__ __forceinline__ void stage_half(const unsigned short* base, int rowoff,
                                           int ktp, int kk, int slot,
                                           int wid, int lane, unsigned char* smem) {
#pragma unroll
  for (int i = 0; i < 2; ++i) {
    int row = wid * 32 + i * 16 + (lane >> 2);
    int kcol8 = (lane & 3) ^ ((row >> 1) & 3);
    const unsigned short* src = base + (size_t)(rowoff + row) * 1024
                                + ktp * 64 + kk * 32 + kcol8 * 8;
    unsigned int doff = (unsigned int)(slot * 16384 + wid * 2048 + i * 1024);
    __builtin_amdgcn_global_load_lds(
        (const __attribute__((address_space(1))) void*)src,
        (__attribute__((address_space(3))) void*)(smem + doff), 16, 0, 0);
  }
}

__device__ __forceinline__ short8 frag_ld(const unsigned char* smem, int slot, int row, int kg) {
  int byte = slot * 16384 + row * 64 + ((kg ^ ((row >> 1) & 3)) * 16);
  return *reinterpret_cast<const short8*>(smem + byte);
}

template <int DT>
__global__ __launch_bounds__(512, 2) void gemm256_kernel(GemmPasses P, void* __restrict__ Cout,
                                                         int N, int NT,
                                                         const float* __restrict__ bias,
                                                         int omode) {
  __shared__ __attribute__((aligned(16))) unsigned char smem[131072];
  const int tid = threadIdx.x;
  const int wid = tid >> 6;
  const int lane = tid & 63;
  const int wm = wid >> 2;
  const int wn = wid & 3;
  const int frow = lane & 15;
  const int kg = lane >> 4;
  const int nwg = gridDim.x * gridDim.y;
  const int wg = blockIdx.y * gridDim.x + blockIdx.x;
  const int swz = (wg & 7) * (nwg >> 3) + (wg >> 3);
  const int brow = (swz / gridDim.x) << 8;
  const int bcol = (swz % gridDim.x) << 8;

  f32x4 acc[8][4];
#pragma unroll
  for (int f = 0; f < 8; ++f)
#pragma unroll
    for (int c = 0; c < 4; ++c)
      acc[f][c] = (f32x4){0.f, 0.f, 0.f, 0.f};

  // prologue: stage halves of tile0 (4) + tile1 A-k0,B-k0,A-k1 (3)
  stage_half(selA(P, 0), brow, 0, 0, 0, wid, lane, smem);
  stage_half(selB(P, 0), bcol, 0, 0, 1, wid, lane, smem);
  stage_half(selA(P, 0), brow, 0, 1, 2, wid, lane, smem);
  stage_half(selB(P, 0), bcol, 0, 1, 3, wid, lane, smem);
  stage_half(selA(P, 0), brow, 1, 0, 4, wid, lane, smem);
  stage_half(selB(P, 0), bcol, 1, 0, 5, wid, lane, smem);
  stage_half(selA(P, 0), brow, 1, 1, 6, wid, lane, smem);
  WAIT_VM6();
  GBAR();

  for (int t = 0; t < NT; ++t) {
    // Horner accumulator fold at pass boundaries (wave-uniform)
    if ((t & 15) == 0 && t != 0) {
      float s = P.sc[t >> 4];
      if (s != 1.0f) {
#pragma unroll
        for (int f = 0; f < 8; ++f)
#pragma unroll
          for (int c = 0; c < 4; ++c)
#pragma unroll
            for (int q = 0; q < 4; ++q)
              acc[f][c][q] *= s;
      }
    }
    const int cur4 = (t & 1) * 4;
    const int nxt4 = cur4 ^ 4;
    short8 a[4], b[4];
    // ---- phase 0: read A-k0 rows0-3 + B-k0; stage B-k1 of tile t+1 ----
#pragma unroll
    for (int f = 0; f < 4; ++f) a[f] = frag_ld(smem, cur4 + 0, wm * 128 + f * 16 + frow, kg);
#pragma unroll
    for (int c = 0; c < 4; ++c) b[c] = frag_ld(smem, cur4 + 1, wn * 64 + c * 16 + frow, kg);
    if (t + 1 < NT) {
      int ts = t + 1;
      stage_half(selB(P, ts >> 4), bcol, ts & 15, 1, nxt4 + 3, wid, lane, smem);
    }
    GBAR();
    __builtin_amdgcn_s_setprio(1);
#pragma unroll
    for (int f = 0; f < 4; ++f)
#pragma unroll
      for (int c = 0; c < 4; ++c)
        acc[f][c] = mma<DT>(a[f], b[c], acc[f][c]);
    __builtin_amdgcn_s_setprio(0);
    GBAR();
    // ---- phase 1: read A-k0 rows4-7; stage A-k0 of tile t+2 ----
#pragma unroll
    for (int f = 0; f < 4; ++f) a[f] = frag_ld(smem, cur4 + 0, wm * 128 + (f + 4) * 16 + frow, kg);
    if (t + 2 < NT) {
      int ts = t + 2;
      stage_half(selA(P, ts >> 4), brow, ts & 15, 0, cur4 + 0, wid, lane, smem);
    }
    GBAR();
    __builtin_amdgcn_s_setprio(1);
#pragma unroll
    for (int f = 0; f < 4; ++f)
#pragma unroll
      for (int c = 0; c < 4; ++c)
        acc[f + 4][c] = mma<DT>(a[f], b[c], acc[f + 4][c]);
    __builtin_amdgcn_s_setprio(0);
    GBAR();
    // ---- phase 2: read A-k1 rows0-3 + B-k1; stage B-k0 of tile t+2 ----
#pragma unroll
    for (int f = 0; f < 4; ++f) a[f] = frag_ld(smem, cur4 + 2, wm * 128 + f * 16 + frow, kg);
#pragma unroll
    for (int c = 0; c < 4; ++c) b[c] = frag_ld(smem, cur4 + 3, wn * 64 + c * 16 + frow, kg);
    if (t + 2 < NT) {
      int ts = t + 2;
      stage_half(selB(P, ts >> 4), bcol, ts & 15, 0, cur4 + 1, wid, lane, smem);
    }
    GBAR();
    __builtin_amdgcn_s_setprio(1);
#pragma unroll
    for (int f = 0; f < 4; ++f)
#pragma unroll
      for (int c = 0; c < 4; ++c)
        acc[f][c] = mma<DT>(a[f], b[c], acc[f][c]);
    __builtin_amdgcn_s_setprio(0);
    GBAR();
    // ---- phase 3: read A-k1 rows4-7; stage A-k1 of tile t+2; vmcnt(6) ----
#pragma unroll
    for (int f = 0; f < 4; ++f) a[f] = frag_ld(smem, cur4 + 2, wm * 128 + (f + 4) * 16 + frow, kg);
    if (t + 2 < NT) {
      int ts = t + 2;
      stage_half(selA(P, ts >> 4), brow, ts & 15, 1, cur4 + 2, wid, lane, smem);
    }
    WAIT_VM6();
    GBAR();
    __builtin_amdgcn_s_setprio(1);
#pragma unroll
    for (int f = 0; f < 4; ++f)
#pragma unroll
      for (int c = 0; c < 4; ++c)
        acc[f + 4][c] = mma<DT>(a[f], b[c], acc[f + 4][c]);
    __builtin_amdgcn_s_setprio(0);
    GBAR();
  }
  WAIT_VM0();

  // epilogue: C/D layout col=lane&15, row=(lane>>4)*4+q
#pragma unroll
  for (int f = 0; f < 8; ++f) {
    int r0 = brow + wm * 128 + f * 16 + kg * 4;
#pragma unroll
    for (int c = 0; c < 4; ++c) {
      int cc = bcol + wn * 64 + c * 16 + frow;
      if (omode == 0) {
        float bb = bias ? bias[cc] : 0.f;
        float* C = (float*)Cout;
#pragma unroll
        for (int q = 0; q < 4; ++q)
          C[(size_t)(r0 + q) * N + cc] = acc[f][c][q] + bb;
      } else {
        unsigned short* C = (unsigned short*)Cout;
#pragma unroll
        for (int q = 0; q < 4; ++q)
          C[(size_t)(r0 + q) * N + cc] = f2h(acc[f][c][q]);
      }
    }
  }
}

// ---------------- WKV scan (fp64 state), windowed chunks over T ----------------
// k fp32 [.,H]; vr fp16 [.,2048] (v at col h, r at col h+1024); out rw fp16.
__global__ void wkv_scan_kernel(const float* __restrict__ kbuf,
                                const unsigned short* __restrict__ vrbuf,
                                const float* __restrict__ tdec,
                                unsigned short* __restrict__ rwh) {
  const int h = blockIdx.x * 64 + threadIdx.x;
  const int chunk = blockIdx.y;
  const int b = blockIdx.z;
  const int t0 = chunk * SCAN_C;
  const int tstart = (chunk == 0) ? 0 : (t0 - SCAN_W);
  const int tend = t0 + SCAN_C;
  double num, den;
  if (chunk == 0) { num = 1.0; den = 1.0; } else { num = 0.0; den = 0.0; }
  const double w = (double)tdec[h];
  size_t ik = ((size_t)b * T_DIM + tstart) * H_DIM + h;
  size_t iv = ((size_t)b * T_DIM + tstart) * 2048 + h;
  float kc = kbuf[ik];
  unsigned short vc = vrbuf[iv];
  unsigned short rc = vrbuf[iv + 1024];
  for (int t = tstart; t < tend; ++t) {
    int adv = (t + 1 < tend) ? 1 : 0;
    float kn = kbuf[ik + adv * H_DIM];
    unsigned short vn = vrbuf[iv + adv * 2048];
    unsigned short rn = vrbuf[iv + adv * 2048 + 1024];
    double ck = (double)kc;
    if (t >= t0) {
      double p = w * ck;
      double A = fma(p, den, num);
      double Bd = den + p;
      float outf = (float)A / (float)Bd;
      float rr = 1.0f / (1.0f + __expf(-h2f(rc)));
      rwh[ik] = f2h(rr * outf);
    }
    double ek = fast_exp64(ck);
    num = fma(w, num, ek * (double)h2f(vc));
    den = fma(w, den, ek);
    kc = kn; vc = vn; rc = rn;
    ik += H_DIM; iv += 2048;
  }
}

// -------------------------------- host --------------------------------
template <int DT>
static inline void run_gemm(const GemmPasses& P, void* C, int Mrows, int N,
                            const float* bias, int omode, hipStream_t stream) {
  gemm256_kernel<DT><<<dim3(N / 256, Mrows / 256), dim3(512), 0, stream>>>(
      P, C, N, P.n * 16, bias, omode);
}

extern "C" void kernel_launch(void* const* d_in, const int* in_sizes, int n_in,
                              void* d_out, int out_size, void* d_ws, size_t ws_size,
                              hipStream_t stream) {
  const float* x    = (const float*)d_in[0];
  const float* tdec = (const float*)d_in[1];
  const float* tmk  = (const float*)d_in[2];
  const float* tmv  = (const float*)d_in[3];
  const float* tmr  = (const float*)d_in[4];
  const float* Wrec = (const float*)d_in[5];
  const float* Wkey = (const float*)d_in[6];
  const float* Wval = (const float*)d_in[7];
  const float* Wout = (const float*)d_in[8];
  const float* bout = (const float*)d_in[9];
  float* out = (float*)d_out;
  unsigned char* ws = (unsigned char*)d_ws;

  const size_t W2 = (size_t)H_DIM * H_DIM * 2;       // 2MB per fp16 weight
  const size_t BF_FULL = (size_t)M_DIM * H_DIM * 2;  // 32MB fp16 [M,H]
  const size_t NEED = 2 * BF_FULL + 2 * BF_FULL + 5 * W2;  // XS(64) + VR(64) + W(10) = 138MB
  if (ws_size < NEED) return;

  size_t off = 0;
  unsigned short* XS1H = (unsigned short*)(ws + off); off += BF_FULL;
  unsigned short* XS2H = (unsigned short*)(ws + off); off += BF_FULL;
  unsigned short* VR   = (unsigned short*)(ws + off); off += 2 * BF_FULL;  // [M,2048] fp16
  unsigned short* WK1H = (unsigned short*)(ws + off); off += W2;
  unsigned short* WK2H = (unsigned short*)(ws + off); off += W2;
  unsigned short* WVRH = (unsigned short*)(ws + off); off += 2 * W2;       // [2048,1024] fp16
  unsigned short* WOH  = (unsigned short*)(ws + off); off += W2;

  wprep_kernel<<<dim3(H_DIM * H_DIM / 256), dim3(256), 0, stream>>>(
      Wrec, Wkey, Wval, Wout, tmk, tmv, tmr, WK1H, WK2H, WVRH, WOH);

  int n4 = M_DIM * (H_DIM / 4);
  xs_split_kernel<<<dim3(n4 / 256), dim3(256), 0, stream>>>(x, XS1H, XS2H, n4);

  // fused v,r projection: one N=2048 fp16 pass -> VR fp16
  GemmPasses Pvr;
  Pvr.n = 1;
  Pvr.A[0] = XS1H; Pvr.B[0] = WVRH; Pvr.sc[0] = 1.f;
  for (int p = 1; p < 6; ++p) { Pvr.A[p] = XS1H; Pvr.B[p] = WVRH; Pvr.sc[p] = 1.f; }
  run_gemm<1>(Pvr, VR, M_DIM, 2 * H_DIM, nullptr, 2, stream);

  // k: 4-pass scaled fp16 double-split (Horner folds), fp32 out into d_out
  const float S11 = 0.00048828125f;  // 2^-11
  GemmPasses Pk;
  Pk.n = 4;
  Pk.A[0] = XS2H; Pk.B[0] = WK2H; Pk.sc[0] = 1.f;    // x2*W2
  Pk.A[1] = XS1H; Pk.B[1] = WK2H; Pk.sc[1] = S11;    // fold, + x1*W2
  Pk.A[2] = XS2H; Pk.B[2] = WK1H; Pk.sc[2] = 1.f;    // + x2*W1
  Pk.A[3] = XS1H; Pk.B[3] = WK1H; Pk.sc[3] = S11;    // fold, + x1*W1
  Pk.A[4] = XS1H; Pk.B[4] = WK1H; Pk.sc[4] = 1.f;
  Pk.A[5] = XS1H; Pk.B[5] = WK1H; Pk.sc[5] = 1.f;
  run_gemm<1>(Pk, out, M_DIM, H_DIM, nullptr, 0, stream);

  // WKV scan; rw (fp16) reuses XS1H (dead after Pk)
  unsigned short* RWH = XS1H;
  wkv_scan_kernel<<<dim3(H_DIM / 64, T_DIM / SCAN_C, B_DIM), dim3(64), 0, stream>>>(
      out, VR, tdec, RWH);

  // final projection + bias -> d_out fp32
  GemmPasses Po;
  Po.n = 1;
  Po.A[0] = RWH; Po.B[0] = WOH; Po.sc[0] = 1.f;
  for (int p = 1; p < 6; ++p) { Po.A[p] = RWH; Po.B[p] = WOH; Po.sc[p] = 1.f; }
  run_gemm<1>(Po, out, M_DIM, H_DIM, bout, 0, stream);
}

// Round 7
// 338.183 us; speedup vs baseline: 3.7474x; 1.0706x over previous
//
#include <hip/hip_runtime.h>

#define H_DIM 1024
#define T_DIM 4096
#define B_DIM 4
#define M_DIM (B_DIM * T_DIM)   // 16384
#define SCAN_C 64
#define SCAN_W 48

typedef __attribute__((ext_vector_type(8))) short short8;
typedef __attribute__((ext_vector_type(4))) float f32x4;
typedef _Float16 half8 __attribute__((ext_vector_type(8)));

__device__ __forceinline__ unsigned short f2h(float f) {
  _Float16 h = (_Float16)f;
  return __builtin_bit_cast(unsigned short, h);
}
__device__ __forceinline__ float h2f(unsigned short u) {
  return (float)__builtin_bit_cast(_Float16, u);
}

__device__ __forceinline__ double fast_exp64(double x) {
  const double L2E = 1.4426950408889634074;
  const double LN2 = 0.69314718055994530942;
  double z = x * L2E;
  double n = rint(z);
  double y = (z - n) * LN2;
  double p = 2.7557319223985890653e-6;
  p = fma(p, y, 2.4801587301587301566e-5);
  p = fma(p, y, 1.9841269841269841253e-4);
  p = fma(p, y, 1.3888888888888889419e-3);
  p = fma(p, y, 8.3333333333333332177e-3);
  p = fma(p, y, 4.1666666666666664354e-2);
  p = fma(p, y, 1.6666666666666665741e-1);
  p = fma(p, y, 0.5);
  p = fma(p, y, 1.0);
  p = fma(p, y, 1.0);
  long long bits = ((long long)(1023 + (int)n)) << 52;
  return p * __longlong_as_double(bits);
}

// ------- xs = x + time_shift(x); scaled fp16 double-split (x1 + x2*2^-11) -------
__global__ void xs_split_kernel(const float* __restrict__ x,
                                unsigned short* __restrict__ xs1,
                                unsigned short* __restrict__ xs2,
                                int n4) {
  int i = blockIdx.x * blockDim.x + threadIdx.x;
  const int HV = H_DIM / 4;
  if (i >= n4) return;
  int m = i / HV;
  int t = m & (T_DIM - 1);
  float4 cur = reinterpret_cast<const float4*>(x)[i];
  float4 prev = make_float4(0.f, 0.f, 0.f, 0.f);
  if (t > 0) prev = reinterpret_cast<const float4*>(x)[i - HV];
  float s[4] = {cur.x + prev.x, cur.y + prev.y, cur.z + prev.z, cur.w + prev.w};
  unsigned short a1[4], a2[4];
#pragma unroll
  for (int q = 0; q < 4; ++q) {
    unsigned short h1 = f2h(s[q]);
    a1[q] = h1;
    a2[q] = f2h((s[q] - h2f(h1)) * 2048.0f);
  }
  reinterpret_cast<ushort4*>(xs1)[i] = make_ushort4(a1[0], a1[1], a1[2], a1[3]);
  reinterpret_cast<ushort4*>(xs2)[i] = make_ushort4(a2[0], a2[1], a2[2], a2[3]);
}

// ------------- weight prep: k = scaled fp16 double-split; v,r,out fp16 -------------
__global__ void wprep_kernel(const float* __restrict__ Wrec, const float* __restrict__ Wkey,
                             const float* __restrict__ Wval, const float* __restrict__ Wout,
                             const float* __restrict__ tmk, const float* __restrict__ tmv,
                             const float* __restrict__ tmr,
                             unsigned short* __restrict__ WK1H, unsigned short* __restrict__ WK2H,
                             unsigned short* __restrict__ WVRH,
                             unsigned short* __restrict__ WOH) {
  int i = blockIdx.x * blockDim.x + threadIdx.x;
  if (i >= H_DIM * H_DIM) return;
  int j = i & (H_DIM - 1);
  float wk = Wkey[i] * tmk[j];
  unsigned short k1 = f2h(wk);
  WK1H[i] = k1;
  WK2H[i] = f2h((wk - h2f(k1)) * 2048.0f);
  WVRH[i] = f2h(Wval[i] * tmv[j]);                    // rows 0..1023: v-weights
  WVRH[H_DIM * H_DIM + i] = f2h(Wrec[i] * tmr[j]);   // rows 1024..2047: r-weights
  WOH[i] = f2h(Wout[i]);
}

// ------------------------- shared helpers -------------------------
#define GBAR() do { asm volatile("" ::: "memory"); __builtin_amdgcn_sched_barrier(0); \
                    __builtin_amdgcn_s_barrier(); \
                    __builtin_amdgcn_sched_barrier(0); asm volatile("" ::: "memory"); } while (0)
#define WAIT_VM6() asm volatile("s_waitcnt vmcnt(6)" ::: "memory")
#define WAIT_VM0() asm volatile("s_waitcnt vmcnt(0)" ::: "memory")

__device__ __forceinline__ f32x4 mma_h(short8 a, short8 b, f32x4 c) {
  return __builtin_amdgcn_mfma_f32_16x16x32_f16(
      __builtin_bit_cast(half8, a), __builtin_bit_cast(half8, b), c, 0, 0, 0);
}
__device__ __forceinline__ f32x4 mma_hh(half8 a, short8 b, f32x4 c) {
  return __builtin_amdgcn_mfma_f32_16x16x32_f16(a, __builtin_bit_cast(half8, b), c, 0, 0, 0);
}

// ============ Pk: 256x128 tile, 4-combo shared-staging fp32-emulated GEMM ============
// k = (XS1+XS2*2^-11) @ (WK1+WK2*2^-11)^T via acc0 = A1B1; acc1 = A1B2+A2B1+(A2*2^-11)B2;
// out = acc0 + 2^-11*acc1.  BK=32, 3-slot LDS ring (48KB/slot), 2-tile stage lead, vmcnt(6).
__device__ __forceinline__ void stage_A32(const unsigned short* base, int rowoff, int kt,
                                          unsigned sbase, int wid, int lane,
                                          unsigned char* smem) {
#pragma unroll
  for (int i = 0; i < 2; ++i) {
    int row = wid * 32 + i * 16 + (lane >> 2);
    int col8 = (lane & 3) ^ ((row >> 1) & 3);
    const unsigned short* src = base + (size_t)(rowoff + row) * 1024 + kt * 32 + col8 * 8;
    __builtin_amdgcn_global_load_lds(
        (const __attribute__((address_space(1))) void*)src,
        (__attribute__((address_space(3))) void*)(smem + sbase + wid * 2048 + i * 1024), 16, 0, 0);
  }
}
__device__ __forceinline__ void stage_B32(const unsigned short* base, int coloff, int kt,
                                          unsigned sbase, int wid, int lane,
                                          unsigned char* smem) {
  int row = wid * 16 + (lane >> 2);
  int col8 = (lane & 3) ^ ((row >> 1) & 3);
  const unsigned short* src = base + (size_t)(coloff + row) * 1024 + kt * 32 + col8 * 8;
  __builtin_amdgcn_global_load_lds(
      (const __attribute__((address_space(1))) void*)src,
      (__attribute__((address_space(3))) void*)(smem + sbase + wid * 1024), 16, 0, 0);
}
__device__ __forceinline__ short8 frag_ld2(const unsigned char* smem, unsigned rbase,
                                           int row, int kg) {
  return *reinterpret_cast<const short8*>(smem + rbase + row * 64 + ((kg ^ ((row >> 1) & 3)) * 16));
}

__global__ __launch_bounds__(512, 2) void gemm_k_kernel(
    const unsigned short* __restrict__ A1, const unsigned short* __restrict__ A2,
    const unsigned short* __restrict__ B1, const unsigned short* __restrict__ B2,
    float* __restrict__ C) {
  __shared__ __attribute__((aligned(16))) unsigned char smem[147456];  // 3 x 48KB
  const int tid = threadIdx.x;
  const int wid = tid >> 6;
  const int lane = tid & 63;
  const int wm = wid >> 2;   // 0..1
  const int wn = wid & 3;    // 0..3
  const int frow = lane & 15;
  const int kg = lane >> 4;
  const int nwg = gridDim.x * gridDim.y;  // 512
  const int wg = blockIdx.y * gridDim.x + blockIdx.x;
  const int swz = (wg & 7) * (nwg >> 3) + (wg >> 3);
  const int brow = (swz / gridDim.x) << 8;   // 256-row tile
  const int bcol = (swz % gridDim.x) << 7;   // 128-col tile

  f32x4 acc0[8][2], acc1[8][2];
#pragma unroll
  for (int f = 0; f < 8; ++f)
#pragma unroll
    for (int c = 0; c < 2; ++c) {
      acc0[f][c] = (f32x4){0.f, 0.f, 0.f, 0.f};
      acc1[f][c] = (f32x4){0.f, 0.f, 0.f, 0.f};
    }

  const int NT = 32;  // K=1024 / BK=32
  // prologue: stage tiles 0,1 (6 loads each)
#pragma unroll
  for (int t0 = 0; t0 < 2; ++t0) {
    unsigned sb = t0 * 49152u;
    stage_A32(A1, brow, t0, sb + 0u, wid, lane, smem);
    stage_A32(A2, brow, t0, sb + 16384u, wid, lane, smem);
    stage_B32(B1, bcol, t0, sb + 32768u, wid, lane, smem);
    stage_B32(B2, bcol, t0, sb + 40960u, wid, lane, smem);
  }
  WAIT_VM6();
  GBAR();

  for (int t = 0; t < NT; ++t) {
    unsigned sb = (unsigned)(t % 3) * 49152u;
    unsigned st = (unsigned)((t + 2) % 3) * 49152u;
    const bool stg = (t + 2 < NT);
    short8 a1[8], a2[8], b1[2], b2[2];
    // ---- P0: read A1 + B1; stage A1(t+2); MFMA acc0 += A1*B1 ----
#pragma unroll
    for (int f = 0; f < 8; ++f) a1[f] = frag_ld2(smem, sb, wm * 128 + f * 16 + frow, kg);
#pragma unroll
    for (int c = 0; c < 2; ++c) b1[c] = frag_ld2(smem, sb + 32768u, wn * 32 + c * 16 + frow, kg);
    if (stg) stage_A32(A1, brow, t + 2, st + 0u, wid, lane, smem);
    GBAR();
    __builtin_amdgcn_s_setprio(1);
#pragma unroll
    for (int f = 0; f < 8; ++f)
#pragma unroll
      for (int c = 0; c < 2; ++c)
        acc0[f][c] = mma_h(a1[f], b1[c], acc0[f][c]);
    __builtin_amdgcn_s_setprio(0);
    GBAR();
    // ---- P1: read B2; stage A2(t+2); MFMA acc1 += A1*B2 ----
#pragma unroll
    for (int c = 0; c < 2; ++c) b2[c] = frag_ld2(smem, sb + 40960u, wn * 32 + c * 16 + frow, kg);
    if (stg) stage_A32(A2, brow, t + 2, st + 16384u, wid, lane, smem);
    GBAR();
    __builtin_amdgcn_s_setprio(1);
#pragma unroll
    for (int f = 0; f < 8; ++f)
#pragma unroll
      for (int c = 0; c < 2; ++c)
        acc1[f][c] = mma_h(a1[f], b2[c], acc1[f][c]);
    __builtin_amdgcn_s_setprio(0);
    GBAR();
    // ---- P2: read A2; stage B1,B2(t+2); MFMA acc1 += A2*B1 ----
#pragma unroll
    for (int f = 0; f < 8; ++f) a2[f] = frag_ld2(smem, sb + 16384u, wm * 128 + f * 16 + frow, kg);
    if (stg) {
      stage_B32(B1, bcol, t + 2, st + 32768u, wid, lane, smem);
      stage_B32(B2, bcol, t + 2, st + 40960u, wid, lane, smem);
    }
    GBAR();
    __builtin_amdgcn_s_setprio(1);
#pragma unroll
    for (int f = 0; f < 8; ++f)
#pragma unroll
      for (int c = 0; c < 2; ++c)
        acc1[f][c] = mma_h(a2[f], b1[c], acc1[f][c]);
    __builtin_amdgcn_s_setprio(0);
    GBAR();
    // ---- P3: acc1 += (A2*2^-11)*B2 (exact pow2 rescale in-register); vmcnt(6) ----
    WAIT_VM6();
    GBAR();
    __builtin_amdgcn_s_setprio(1);
#pragma unroll
    for (int f = 0; f < 8; ++f) {
      half8 ad = __builtin_bit_cast(half8, a2[f]) * (_Float16)0.00048828125f;
#pragma unroll
      for (int c = 0; c < 2; ++c)
        acc1[f][c] = mma_hh(ad, b2[c], acc1[f][c]);
    }
    __builtin_amdgcn_s_setprio(0);
    GBAR();
  }
  WAIT_VM0();

  // epilogue: out = acc0 + 2^-11 * acc1; C/D layout col=lane&15, row=(lane>>4)*4+q
#pragma unroll
  for (int f = 0; f < 8; ++f) {
    int r0 = brow + wm * 128 + f * 16 + kg * 4;
#pragma unroll
    for (int c = 0; c < 2; ++c) {
      int cc = bcol + wn * 32 + c * 16 + frow;
#pragma unroll
      for (int q = 0; q < 4; ++q)
        C[(size_t)(r0 + q) * H_DIM + cc] =
            fmaf(0.00048828125f, acc1[f][c][q], acc0[f][c][q]);
    }
  }
}

// =================== 256x256 8-phase fp16 GEMM (Pvr, Po) ===================
struct GemmPasses {
  const unsigned short* A[2];
  const unsigned short* B[2];
  int n;
};

__device__ __forceinline__ void stage_half(const unsigned short* base, int rowoff,
                                           int ktp, int kk, int slot,
                                           int wid, int lane, unsigned char* smem) {
#pragma unroll
  for (int i = 0; i < 2; ++i) {
    int row = wid * 32 + i * 16 + (lane >> 2);
    int kcol8 = (lane & 3) ^ ((row >> 1) & 3);
    const unsigned short* src = base + (size_t)(rowoff + row) * 1024
                                + ktp * 64 + kk * 32 + kcol8 * 8;
    unsigned int doff = (unsigned int)(slot * 16384 + wid * 2048 + i * 1024);
    __builtin_amdgcn_global_load_lds(
        (const __attribute__((address_space(1))) void*)src,
        (__attribute__((address_space(3))) void*)(smem + doff), 16, 0, 0);
  }
}
__device__ __forceinline__ short8 frag_ld(const unsigned char* smem, int slot, int row, int kg) {
  int byte = slot * 16384 + row * 64 + ((kg ^ ((row >> 1) & 3)) * 16);
  return *reinterpret_cast<const short8*>(smem + byte);
}

__global__ __launch_bounds__(512, 2) void gemm256_kernel(GemmPasses P, void* __restrict__ Cout,
                                                         int N, int NT,
                                                         const float* __restrict__ bias,
                                                         int omode) {
  __shared__ __attribute__((aligned(16))) unsigned char smem[131072];
  const int tid = threadIdx.x;
  const int wid = tid >> 6;
  const int lane = tid & 63;
  const int wm = wid >> 2;
  const int wn = wid & 3;
  const int frow = lane & 15;
  const int kg = lane >> 4;
  const int nwg = gridDim.x * gridDim.y;
  const int wg = blockIdx.y * gridDim.x + blockIdx.x;
  const int swz = (wg & 7) * (nwg >> 3) + (wg >> 3);
  const int brow = (swz / gridDim.x) << 8;
  const int bcol = (swz % gridDim.x) << 8;

  f32x4 acc[8][4];
#pragma unroll
  for (int f = 0; f < 8; ++f)
#pragma unroll
    for (int c = 0; c < 4; ++c)
      acc[f][c] = (f32x4){0.f, 0.f, 0.f, 0.f};

  const unsigned short* Ag = P.A[0];
  const unsigned short* Bg = P.B[0];
  stage_half(Ag, brow, 0, 0, 0, wid, lane, smem);
  stage_half(Bg, bcol, 0, 0, 1, wid, lane, smem);
  stage_half(Ag, brow, 0, 1, 2, wid, lane, smem);
  stage_half(Bg, bcol, 0, 1, 3, wid, lane, smem);
  stage_half(Ag, brow, 1, 0, 4, wid, lane, smem);
  stage_half(Bg, bcol, 1, 0, 5, wid, lane, smem);
  stage_half(Ag, brow, 1, 1, 6, wid, lane, smem);
  WAIT_VM6();
  GBAR();

  for (int t = 0; t < NT; ++t) {
    const int cur4 = (t & 1) * 4;
    const int nxt4 = cur4 ^ 4;
    const unsigned short* Agp = P.A[(t >> 4) >= P.n ? P.n - 1 : (t >> 4)];
    const unsigned short* Bgp = P.B[(t >> 4) >= P.n ? P.n - 1 : (t >> 4)];
    short8 a[4], b[4];
#pragma unroll
    for (int f = 0; f < 4; ++f) a[f] = frag_ld(smem, cur4 + 0, wm * 128 + f * 16 + frow, kg);
#pragma unroll
    for (int c = 0; c < 4; ++c) b[c] = frag_ld(smem, cur4 + 1, wn * 64 + c * 16 + frow, kg);
    if (t + 1 < NT) {
      int ts = t + 1;
      stage_half(P.B[(ts >> 4)], bcol, ts & 15, 1, nxt4 + 3, wid, lane, smem);
    }
    GBAR();
    __builtin_amdgcn_s_setprio(1);
#pragma unroll
    for (int f = 0; f < 4; ++f)
#pragma unroll
      for (int c = 0; c < 4; ++c)
        acc[f][c] = mma_h(a[f], b[c], acc[f][c]);
    __builtin_amdgcn_s_setprio(0);
    GBAR();
#pragma unroll
    for (int f = 0; f < 4; ++f) a[f] = frag_ld(smem, cur4 + 0, wm * 128 + (f + 4) * 16 + frow, kg);
    if (t + 2 < NT) {
      int ts = t + 2;
      stage_half(P.A[(ts >> 4)], brow, ts & 15, 0, cur4 + 0, wid, lane, smem);
    }
    GBAR();
    __builtin_amdgcn_s_setprio(1);
#pragma unroll
    for (int f = 0; f < 4; ++f)
#pragma unroll
      for (int c = 0; c < 4; ++c)
        acc[f + 4][c] = mma_h(a[f], b[c], acc[f + 4][c]);
    __builtin_amdgcn_s_setprio(0);
    GBAR();
#pragma unroll
    for (int f = 0; f < 4; ++f) a[f] = frag_ld(smem, cur4 + 2, wm * 128 + f * 16 + frow, kg);
#pragma unroll
    for (int c = 0; c < 4; ++c) b[c] = frag_ld(smem, cur4 + 3, wn * 64 + c * 16 + frow, kg);
    if (t + 2 < NT) {
      int ts = t + 2;
      stage_half(P.B[(ts >> 4)], bcol, ts & 15, 0, cur4 + 1, wid, lane, smem);
    }
    GBAR();
    __builtin_amdgcn_s_setprio(1);
#pragma unroll
    for (int f = 0; f < 4; ++f)
#pragma unroll
      for (int c = 0; c < 4; ++c)
        acc[f][c] = mma_h(a[f], b[c], acc[f][c]);
    __builtin_amdgcn_s_setprio(0);
    GBAR();
#pragma unroll
    for (int f = 0; f < 4; ++f) a[f] = frag_ld(smem, cur4 + 2, wm * 128 + (f + 4) * 16 + frow, kg);
    if (t + 2 < NT) {
      int ts = t + 2;
      stage_half(P.A[(ts >> 4)], brow, ts & 15, 1, cur4 + 2, wid, lane, smem);
    }
    WAIT_VM6();
    GBAR();
    __builtin_amdgcn_s_setprio(1);
#pragma unroll
    for (int f = 0; f < 4; ++f)
#pragma unroll
      for (int c = 0; c < 4; ++c)
        acc[f + 4][c] = mma_h(a[f], b[c], acc[f + 4][c]);
    __builtin_amdgcn_s_setprio(0);
    GBAR();
  }
  WAIT_VM0();

#pragma unroll
  for (int f = 0; f < 8; ++f) {
    int r0 = brow + wm * 128 + f * 16 + kg * 4;
#pragma unroll
    for (int c = 0; c < 4; ++c) {
      int cc = bcol + wn * 64 + c * 16 + frow;
      if (omode == 0) {
        float bb = bias ? bias[cc] : 0.f;
        float* C = (float*)Cout;
#pragma unroll
        for (int q = 0; q < 4; ++q)
          C[(size_t)(r0 + q) * N + cc] = acc[f][c][q] + bb;
      } else {
        unsigned short* C = (unsigned short*)Cout;
#pragma unroll
        for (int q = 0; q < 4; ++q)
          C[(size_t)(r0 + q) * N + cc] = f2h(acc[f][c][q]);
      }
    }
  }
}

// ---------------- WKV scan (fp64 state), windowed chunks over T ----------------
__global__ void wkv_scan_kernel(const float* __restrict__ kbuf,
                                const unsigned short* __restrict__ vrbuf,
                                const float* __restrict__ tdec,
                                unsigned short* __restrict__ rwh) {
  const int h = blockIdx.x * 64 + threadIdx.x;
  const int chunk = blockIdx.y;
  const int b = blockIdx.z;
  const int t0 = chunk * SCAN_C;
  const int tstart = (chunk == 0) ? 0 : (t0 - SCAN_W);
  const int tend = t0 + SCAN_C;
  double num, den;
  if (chunk == 0) { num = 1.0; den = 1.0; } else { num = 0.0; den = 0.0; }
  const double w = (double)tdec[h];
  size_t ik = ((size_t)b * T_DIM + tstart) * H_DIM + h;
  size_t iv = ((size_t)b * T_DIM + tstart) * 2048 + h;
  float kc = kbuf[ik];
  unsigned short vc = vrbuf[iv];
  unsigned short rc = vrbuf[iv + 1024];
  for (int t = tstart; t < tend; ++t) {
    int adv = (t + 1 < tend) ? 1 : 0;
    float kn = kbuf[ik + adv * H_DIM];
    unsigned short vn = vrbuf[iv + adv * 2048];
    unsigned short rn = vrbuf[iv + adv * 2048 + 1024];
    double ck = (double)kc;
    if (t >= t0) {
      double p = w * ck;
      double A = fma(p, den, num);
      double Bd = den + p;
      float outf = (float)A / (float)Bd;
      float rr = 1.0f / (1.0f + __expf(-h2f(rc)));
      rwh[ik] = f2h(rr * outf);
    }
    double ek = fast_exp64(ck);
    num = fma(w, num, ek * (double)h2f(vc));
    den = fma(w, den, ek);
    kc = kn; vc = vn; rc = rn;
    ik += H_DIM; iv += 2048;
  }
}

// -------------------------------- host --------------------------------
static inline void run_gemm256(const GemmPasses& P, void* C, int Mrows, int N,
                               const float* bias, int omode, hipStream_t stream) {
  gemm256_kernel<<<dim3(N / 256, Mrows / 256), dim3(512), 0, stream>>>(
      P, C, N, P.n * 16, bias, omode);
}

extern "C" void kernel_launch(void* const* d_in, const int* in_sizes, int n_in,
                              void* d_out, int out_size, void* d_ws, size_t ws_size,
                              hipStream_t stream) {
  const float* x    = (const float*)d_in[0];
  const float* tdec = (const float*)d_in[1];
  const float* tmk  = (const float*)d_in[2];
  const float* tmv  = (const float*)d_in[3];
  const float* tmr  = (const float*)d_in[4];
  const float* Wrec = (const float*)d_in[5];
  const float* Wkey = (const float*)d_in[6];
  const float* Wval = (const float*)d_in[7];
  const float* Wout = (const float*)d_in[8];
  const float* bout = (const float*)d_in[9];
  float* out = (float*)d_out;
  unsigned char* ws = (unsigned char*)d_ws;

  const size_t W2 = (size_t)H_DIM * H_DIM * 2;       // 2MB per fp16 weight
  const size_t BF_FULL = (size_t)M_DIM * H_DIM * 2;  // 32MB fp16 [M,H]
  const size_t NEED = 2 * BF_FULL + 2 * BF_FULL + 5 * W2;  // 138MB
  if (ws_size < NEED) return;

  size_t off = 0;
  unsigned short* XS1H = (unsigned short*)(ws + off); off += BF_FULL;
  unsigned short* XS2H = (unsigned short*)(ws + off); off += BF_FULL;
  unsigned short* VR   = (unsigned short*)(ws + off); off += 2 * BF_FULL;  // [M,2048] fp16
  unsigned short* WK1H = (unsigned short*)(ws + off); off += W2;
  unsigned short* WK2H = (unsigned short*)(ws + off); off += W2;
  unsigned short* WVRH = (unsigned short*)(ws + off); off += 2 * W2;       // [2048,1024] fp16
  unsigned short* WOH  = (unsigned short*)(ws + off); off += W2;

  wprep_kernel<<<dim3(H_DIM * H_DIM / 256), dim3(256), 0, stream>>>(
      Wrec, Wkey, Wval, Wout, tmk, tmv, tmr, WK1H, WK2H, WVRH, WOH);

  int n4 = M_DIM * (H_DIM / 4);
  xs_split_kernel<<<dim3(n4 / 256), dim3(256), 0, stream>>>(x, XS1H, XS2H, n4);

  // fused v,r projection: one N=2048 fp16 pass -> VR fp16
  GemmPasses Pvr;
  Pvr.n = 1;
  Pvr.A[0] = XS1H; Pvr.B[0] = WVRH; Pvr.A[1] = XS1H; Pvr.B[1] = WVRH;
  run_gemm256(Pvr, VR, M_DIM, 2 * H_DIM, nullptr, 2, stream);

  // k: 4-combo shared-staging fp32-emulated GEMM -> d_out fp32
  gemm_k_kernel<<<dim3(H_DIM / 128, M_DIM / 256), dim3(512), 0, stream>>>(
      XS1H, XS2H, WK1H, WK2H, out);

  // WKV scan; rw (fp16) reuses XS1H (dead after Pk)
  unsigned short* RWH = XS1H;
  wkv_scan_kernel<<<dim3(H_DIM / 64, T_DIM / SCAN_C, B_DIM), dim3(64), 0, stream>>>(
      out, VR, tdec, RWH);

  // final projection + bias -> d_out fp32
  GemmPasses Po;
  Po.n = 1;
  Po.A[0] = RWH; Po.B[0] = WOH; Po.A[1] = RWH; Po.B[1] = WOH;
  run_gemm256(Po, out, M_DIM, H_DIM, bout, 0, stream);
}

// Round 8
// 322.160 us; speedup vs baseline: 3.9338x; 1.0497x over previous
//
#include <hip/hip_runtime.h>

#define H_DIM 1024
#define T_DIM 4096
#define B_DIM 4
#define M_DIM (B_DIM * T_DIM)   // 16384
#define SCAN_C 64
#define SCAN_W 48

typedef __attribute__((ext_vector_type(8))) short short8;
typedef __attribute__((ext_vector_type(4))) float f32x4;
typedef _Float16 half8 __attribute__((ext_vector_type(8)));

__device__ __forceinline__ unsigned short f2h(float f) {
  _Float16 h = (_Float16)f;
  return __builtin_bit_cast(unsigned short, h);
}
__device__ __forceinline__ float h2f(unsigned short u) {
  return (float)__builtin_bit_cast(_Float16, u);
}

__device__ __forceinline__ double fast_exp64(double x) {
  const double L2E = 1.4426950408889634074;
  const double LN2 = 0.69314718055994530942;
  double z = x * L2E;
  double n = rint(z);
  double y = (z - n) * LN2;
  double p = 2.7557319223985890653e-6;
  p = fma(p, y, 2.4801587301587301566e-5);
  p = fma(p, y, 1.9841269841269841253e-4);
  p = fma(p, y, 1.3888888888888889419e-3);
  p = fma(p, y, 8.3333333333333332177e-3);
  p = fma(p, y, 4.1666666666666664354e-2);
  p = fma(p, y, 1.6666666666666665741e-1);
  p = fma(p, y, 0.5);
  p = fma(p, y, 1.0);
  p = fma(p, y, 1.0);
  long long bits = ((long long)(1023 + (int)n)) << 52;
  return p * __longlong_as_double(bits);
}

// ------- xs = x + time_shift(x); scaled fp16 double-split (x1 + x2*2^-11) -------
__global__ void xs_split_kernel(const float* __restrict__ x,
                                unsigned short* __restrict__ xs1,
                                unsigned short* __restrict__ xs2,
                                int n4) {
  int i = blockIdx.x * blockDim.x + threadIdx.x;
  const int HV = H_DIM / 4;
  if (i >= n4) return;
  int m = i / HV;
  int t = m & (T_DIM - 1);
  float4 cur = reinterpret_cast<const float4*>(x)[i];
  float4 prev = make_float4(0.f, 0.f, 0.f, 0.f);
  if (t > 0) prev = reinterpret_cast<const float4*>(x)[i - HV];
  float s[4] = {cur.x + prev.x, cur.y + prev.y, cur.z + prev.z, cur.w + prev.w};
  unsigned short a1[4], a2[4];
#pragma unroll
  for (int q = 0; q < 4; ++q) {
    unsigned short h1 = f2h(s[q]);
    a1[q] = h1;
    a2[q] = f2h((s[q] - h2f(h1)) * 2048.0f);
  }
  reinterpret_cast<ushort4*>(xs1)[i] = make_ushort4(a1[0], a1[1], a1[2], a1[3]);
  reinterpret_cast<ushort4*>(xs2)[i] = make_ushort4(a2[0], a2[1], a2[2], a2[3]);
}

// ------------- weight prep: k = scaled fp16 double-split; v,r,out fp16 -------------
__global__ void wprep_kernel(const float* __restrict__ Wrec, const float* __restrict__ Wkey,
                             const float* __restrict__ Wval, const float* __restrict__ Wout,
                             const float* __restrict__ tmk, const float* __restrict__ tmv,
                             const float* __restrict__ tmr,
                             unsigned short* __restrict__ WK1H, unsigned short* __restrict__ WK2H,
                             unsigned short* __restrict__ WVRH,
                             unsigned short* __restrict__ WOH) {
  int i = blockIdx.x * blockDim.x + threadIdx.x;
  if (i >= H_DIM * H_DIM) return;
  int j = i & (H_DIM - 1);
  float wk = Wkey[i] * tmk[j];
  unsigned short k1 = f2h(wk);
  WK1H[i] = k1;
  WK2H[i] = f2h((wk - h2f(k1)) * 2048.0f);
  WVRH[i] = f2h(Wval[i] * tmv[j]);                    // rows 0..1023: v-weights
  WVRH[H_DIM * H_DIM + i] = f2h(Wrec[i] * tmr[j]);   // rows 1024..2047: r-weights
  WOH[i] = f2h(Wout[i]);
}

// ------------------------- shared helpers -------------------------
#define GBAR() do { asm volatile("" ::: "memory"); __builtin_amdgcn_sched_barrier(0); \
                    __builtin_amdgcn_s_barrier(); \
                    __builtin_amdgcn_sched_barrier(0); asm volatile("" ::: "memory"); } while (0)
#define WAIT_VM6() asm volatile("s_waitcnt vmcnt(6)" ::: "memory")
#define WAIT_VM0() asm volatile("s_waitcnt vmcnt(0)" ::: "memory")

__device__ __forceinline__ f32x4 mma_h(short8 a, short8 b, f32x4 c) {
  return __builtin_amdgcn_mfma_f32_16x16x32_f16(
      __builtin_bit_cast(half8, a), __builtin_bit_cast(half8, b), c, 0, 0, 0);
}
__device__ __forceinline__ f32x4 mma_hh(half8 a, short8 b, f32x4 c) {
  return __builtin_amdgcn_mfma_f32_16x16x32_f16(a, __builtin_bit_cast(half8, b), c, 0, 0, 0);
}

// stage 128 rows x 32 cols (8KB): 1 load/thread; linear LDS, inverse-swz source
__device__ __forceinline__ void stage_r128(const unsigned short* base, int rowoff, int kt,
                                           unsigned dst, int wid, int lane,
                                           unsigned char* smem) {
  int row = wid * 16 + (lane >> 2);
  int col8 = (lane & 3) ^ ((row >> 1) & 3);
  const unsigned short* src = base + (size_t)(rowoff + row) * 1024 + kt * 32 + col8 * 8;
  __builtin_amdgcn_global_load_lds(
      (const __attribute__((address_space(1))) void*)src,
      (__attribute__((address_space(3))) void*)(smem + dst + wid * 1024), 16, 0, 0);
}
// stage 256 rows x 32 cols (16KB): 2 loads/thread
__device__ __forceinline__ void stage_r256(const unsigned short* base, int rowoff, int kt,
                                           unsigned dst, int wid, int lane,
                                           unsigned char* smem) {
#pragma unroll
  for (int i = 0; i < 2; ++i) {
    int row = wid * 32 + i * 16 + (lane >> 2);
    int col8 = (lane & 3) ^ ((row >> 1) & 3);
    const unsigned short* src = base + (size_t)(rowoff + row) * 1024 + kt * 32 + col8 * 8;
    __builtin_amdgcn_global_load_lds(
        (const __attribute__((address_space(1))) void*)src,
        (__attribute__((address_space(3))) void*)(smem + dst + wid * 2048 + i * 1024), 16, 0, 0);
  }
}
__device__ __forceinline__ short8 frag_ld2(const unsigned char* smem, unsigned rbase,
                                           int row, int kg) {
  return *reinterpret_cast<const short8*>(smem + rbase + row * 64 + ((kg ^ ((row >> 1) & 3)) * 16));
}

// ============ k-role: 128x256 tile, 4-combo fp32-emulated GEMM, 2 phases/tile ============
// k = (XS1+XS2*2^-11) @ (WK1+WK2*2^-11)^T:
//   acc0 = A1B1; acc1 = A1B2 + A2B1 + (A2*2^-11)B2; out = acc0 + 2^-11*acc1.
// BK=32, 3-slot LDS ring (48KB: A1|A2|B1|B2 = 8+8+16+16KB), 2-tile lead, vmcnt(6)/tile.
__device__ void gemm_k_body(const unsigned short* __restrict__ A1,
                            const unsigned short* __restrict__ A2,
                            const unsigned short* __restrict__ B1,
                            const unsigned short* __restrict__ B2,
                            float* __restrict__ C, int bid, unsigned char* smem) {
  const int tid = threadIdx.x;
  const int wid = tid >> 6;
  const int lane = tid & 63;
  const int wm = wid >> 2;   // 0..1 -> 64 rows each
  const int wn = wid & 3;    // 0..3 -> 64 cols each
  const int frow = lane & 15;
  const int kg = lane >> 4;
  const int swz = (bid & 7) * 64 + (bid >> 3);   // nwg=512, bijective
  const int brow = (swz >> 2) << 7;   // 128-row tile, 128 row-blocks
  const int bcol = (swz & 3) << 8;    // 256-col tile, 4 col-blocks

  f32x4 acc0[4][4], acc1[4][4];
#pragma unroll
  for (int f = 0; f < 4; ++f)
#pragma unroll
    for (int c = 0; c < 4; ++c) {
      acc0[f][c] = (f32x4){0.f, 0.f, 0.f, 0.f};
      acc1[f][c] = (f32x4){0.f, 0.f, 0.f, 0.f};
    }

  const int NT = 32;  // K=1024 / BK=32
#pragma unroll
  for (int t0 = 0; t0 < 2; ++t0) {
    unsigned sb = t0 * 49152u;
    stage_r128(A1, brow, t0, sb + 0u, wid, lane, smem);
    stage_r128(A2, brow, t0, sb + 8192u, wid, lane, smem);
    stage_r256(B1, bcol, t0, sb + 16384u, wid, lane, smem);
    stage_r256(B2, bcol, t0, sb + 32768u, wid, lane, smem);
  }
  WAIT_VM6();
  GBAR();

  for (int t = 0; t < NT; ++t) {
    unsigned sb = (unsigned)(t % 3) * 49152u;
    unsigned st = (unsigned)((t + 2) % 3) * 49152u;
    const bool stg = (t + 2 < NT);
    short8 a1[4], a2[4], b1[4], b2[4];
    // ---- P0: read a1,b1,b2 (12); stage A1,A2(t+2); 32 MFMA ----
#pragma unroll
    for (int f = 0; f < 4; ++f) a1[f] = frag_ld2(smem, sb + 0u, wm * 64 + f * 16 + frow, kg);
#pragma unroll
    for (int c = 0; c < 4; ++c) b1[c] = frag_ld2(smem, sb + 16384u, wn * 64 + c * 16 + frow, kg);
#pragma unroll
    for (int c = 0; c < 4; ++c) b2[c] = frag_ld2(smem, sb + 32768u, wn * 64 + c * 16 + frow, kg);
    if (stg) {
      stage_r128(A1, brow, t + 2, st + 0u, wid, lane, smem);
      stage_r128(A2, brow, t + 2, st + 8192u, wid, lane, smem);
    }
    GBAR();
    __builtin_amdgcn_s_setprio(1);
#pragma unroll
    for (int f = 0; f < 4; ++f)
#pragma unroll
      for (int c = 0; c < 4; ++c)
        acc0[f][c] = mma_h(a1[f], b1[c], acc0[f][c]);
#pragma unroll
    for (int f = 0; f < 4; ++f)
#pragma unroll
      for (int c = 0; c < 4; ++c)
        acc1[f][c] = mma_h(a1[f], b2[c], acc1[f][c]);
    __builtin_amdgcn_s_setprio(0);
    GBAR();
    // ---- P1: read a2 (4); stage B1,B2(t+2); vmcnt(6); 32 MFMA ----
#pragma unroll
    for (int f = 0; f < 4; ++f) a2[f] = frag_ld2(smem, sb + 8192u, wm * 64 + f * 16 + frow, kg);
    if (stg) {
      stage_r256(B1, bcol, t + 2, st + 16384u, wid, lane, smem);
      stage_r256(B2, bcol, t + 2, st + 32768u, wid, lane, smem);
    }
    WAIT_VM6();
    GBAR();
    __builtin_amdgcn_s_setprio(1);
#pragma unroll
    for (int f = 0; f < 4; ++f)
#pragma unroll
      for (int c = 0; c < 4; ++c)
        acc1[f][c] = mma_h(a2[f], b1[c], acc1[f][c]);
#pragma unroll
    for (int f = 0; f < 4; ++f) {
      half8 ad = __builtin_bit_cast(half8, a2[f]) * (_Float16)0.00048828125f;
#pragma unroll
      for (int c = 0; c < 4; ++c)
        acc1[f][c] = mma_hh(ad, b2[c], acc1[f][c]);
    }
    __builtin_amdgcn_s_setprio(0);
    GBAR();
  }
  WAIT_VM0();

  // out = acc0 + 2^-11*acc1; C/D layout col=lane&15, row=(lane>>4)*4+q
#pragma unroll
  for (int f = 0; f < 4; ++f) {
    int r0 = brow + wm * 64 + f * 16 + kg * 4;
#pragma unroll
    for (int c = 0; c < 4; ++c) {
      int cc = bcol + wn * 64 + c * 16 + frow;
#pragma unroll
      for (int q = 0; q < 4; ++q)
        C[(size_t)(r0 + q) * H_DIM + cc] =
            fmaf(0.00048828125f, acc1[f][c][q], acc0[f][c][q]);
    }
  }
}

// ============ vr-role: 256x256 8-phase fp16 GEMM, N=2048, fp16 out ============
__device__ __forceinline__ void stage_half(const unsigned short* base, int rowoff,
                                           int ktp, int kk, int slot,
                                           int wid, int lane, unsigned char* smem) {
#pragma unroll
  for (int i = 0; i < 2; ++i) {
    int row = wid * 32 + i * 16 + (lane >> 2);
    int kcol8 = (lane & 3) ^ ((row >> 1) & 3);
    const unsigned short* src = base + (size_t)(rowoff + row) * 1024
                                + ktp * 64 + kk * 32 + kcol8 * 8;
    unsigned int doff = (unsigned int)(slot * 16384 + wid * 2048 + i * 1024);
    __builtin_amdgcn_global_load_lds(
        (const __attribute__((address_space(1))) void*)src,
        (__attribute__((address_space(3))) void*)(smem + doff), 16, 0, 0);
  }
}
__device__ __forceinline__ short8 frag_ld(const unsigned char* smem, int slot, int row, int kg) {
  int byte = slot * 16384 + row * 64 + ((kg ^ ((row >> 1) & 3)) * 16);
  return *reinterpret_cast<const short8*>(smem + byte);
}

__device__ void gemm_vr_body(const unsigned short* __restrict__ Ag,
                             const unsigned short* __restrict__ Bg,
                             unsigned short* __restrict__ C, int bid,
                             unsigned char* smem) {
  const int tid = threadIdx.x;
  const int wid = tid >> 6;
  const int lane = tid & 63;
  const int wm = wid >> 2;
  const int wn = wid & 3;
  const int frow = lane & 15;
  const int kg = lane >> 4;
  const int swz = (bid & 7) * 64 + (bid >> 3);   // nwg=512
  const int brow = (swz >> 3) << 8;   // 64 row-blocks
  const int bcol = (swz & 7) << 8;    // 8 col-blocks (N=2048)

  f32x4 acc[8][4];
#pragma unroll
  for (int f = 0; f < 8; ++f)
#pragma unroll
    for (int c = 0; c < 4; ++c)
      acc[f][c] = (f32x4){0.f, 0.f, 0.f, 0.f};

  const int NT = 16;
  stage_half(Ag, brow, 0, 0, 0, wid, lane, smem);
  stage_half(Bg, bcol, 0, 0, 1, wid, lane, smem);
  stage_half(Ag, brow, 0, 1, 2, wid, lane, smem);
  stage_half(Bg, bcol, 0, 1, 3, wid, lane, smem);
  stage_half(Ag, brow, 1, 0, 4, wid, lane, smem);
  stage_half(Bg, bcol, 1, 0, 5, wid, lane, smem);
  stage_half(Ag, brow, 1, 1, 6, wid, lane, smem);
  WAIT_VM6();
  GBAR();

  for (int t = 0; t < NT; ++t) {
    const int cur4 = (t & 1) * 4;
    const int nxt4 = cur4 ^ 4;
    short8 a[4], b[4];
#pragma unroll
    for (int f = 0; f < 4; ++f) a[f] = frag_ld(smem, cur4 + 0, wm * 128 + f * 16 + frow, kg);
#pragma unroll
    for (int c = 0; c < 4; ++c) b[c] = frag_ld(smem, cur4 + 1, wn * 64 + c * 16 + frow, kg);
    if (t + 1 < NT) stage_half(Bg, bcol, t + 1, 1, nxt4 + 3, wid, lane, smem);
    GBAR();
    __builtin_amdgcn_s_setprio(1);
#pragma unroll
    for (int f = 0; f < 4; ++f)
#pragma unroll
      for (int c = 0; c < 4; ++c)
        acc[f][c] = mma_h(a[f], b[c], acc[f][c]);
    __builtin_amdgcn_s_setprio(0);
    GBAR();
#pragma unroll
    for (int f = 0; f < 4; ++f) a[f] = frag_ld(smem, cur4 + 0, wm * 128 + (f + 4) * 16 + frow, kg);
    if (t + 2 < NT) stage_half(Ag, brow, t + 2, 0, cur4 + 0, wid, lane, smem);
    GBAR();
    __builtin_amdgcn_s_setprio(1);
#pragma unroll
    for (int f = 0; f < 4; ++f)
#pragma unroll
      for (int c = 0; c < 4; ++c)
        acc[f + 4][c] = mma_h(a[f], b[c], acc[f + 4][c]);
    __builtin_amdgcn_s_setprio(0);
    GBAR();
#pragma unroll
    for (int f = 0; f < 4; ++f) a[f] = frag_ld(smem, cur4 + 2, wm * 128 + f * 16 + frow, kg);
#pragma unroll
    for (int c = 0; c < 4; ++c) b[c] = frag_ld(smem, cur4 + 3, wn * 64 + c * 16 + frow, kg);
    if (t + 2 < NT) stage_half(Bg, bcol, t + 2, 0, cur4 + 1, wid, lane, smem);
    GBAR();
    __builtin_amdgcn_s_setprio(1);
#pragma unroll
    for (int f = 0; f < 4; ++f)
#pragma unroll
      for (int c = 0; c < 4; ++c)
        acc[f][c] = mma_h(a[f], b[c], acc[f][c]);
    __builtin_amdgcn_s_setprio(0);
    GBAR();
#pragma unroll
    for (int f = 0; f < 4; ++f) a[f] = frag_ld(smem, cur4 + 2, wm * 128 + (f + 4) * 16 + frow, kg);
    if (t + 2 < NT) stage_half(Ag, brow, t + 2, 1, cur4 + 2, wid, lane, smem);
    WAIT_VM6();
    GBAR();
    __builtin_amdgcn_s_setprio(1);
#pragma unroll
    for (int f = 0; f < 4; ++f)
#pragma unroll
      for (int c = 0; c < 4; ++c)
        acc[f + 4][c] = mma_h(a[f], b[c], acc[f + 4][c]);
    __builtin_amdgcn_s_setprio(0);
    GBAR();
  }
  WAIT_VM0();

#pragma unroll
  for (int f = 0; f < 8; ++f) {
    int r0 = brow + wm * 128 + f * 16 + kg * 4;
#pragma unroll
    for (int c = 0; c < 4; ++c) {
      int cc = bcol + wn * 64 + c * 16 + frow;
#pragma unroll
      for (int q = 0; q < 4; ++q)
        C[(size_t)(r0 + q) * 2048 + cc] = f2h(acc[f][c][q]);
    }
  }
}

// fused front dispatch: blocks 0..511 compute k (fp32 -> Ck), 512..1023 compute v|r (fp16 -> Cvr)
__global__ __launch_bounds__(512, 2) void front_kernel(
    const unsigned short* __restrict__ XS1, const unsigned short* __restrict__ XS2,
    const unsigned short* __restrict__ WK1, const unsigned short* __restrict__ WK2,
    const unsigned short* __restrict__ WVR,
    float* __restrict__ Ck, unsigned short* __restrict__ Cvr) {
  __shared__ __attribute__((aligned(16))) unsigned char smem[147456];
  int bid = blockIdx.x;
  if (bid < 512)
    gemm_k_body(XS1, XS2, WK1, WK2, Ck, bid, smem);
  else
    gemm_vr_body(XS1, WVR, Cvr, bid - 512, smem);
}

// =================== Po: 256x256 8-phase fp16 GEMM, fp32 out + bias ===================
__global__ __launch_bounds__(512, 2) void gemm_o_kernel(const unsigned short* __restrict__ Ag,
                                                        const unsigned short* __restrict__ Bg,
                                                        float* __restrict__ C,
                                                        const float* __restrict__ bias) {
  __shared__ __attribute__((aligned(16))) unsigned char smem[131072];
  const int tid = threadIdx.x;
  const int wid = tid >> 6;
  const int lane = tid & 63;
  const int wm = wid >> 2;
  const int wn = wid & 3;
  const int frow = lane & 15;
  const int kg = lane >> 4;
  const int nwg = gridDim.x * gridDim.y;   // 256
  const int wg = blockIdx.y * gridDim.x + blockIdx.x;
  const int swz = (wg & 7) * (nwg >> 3) + (wg >> 3);
  const int brow = (swz / gridDim.x) << 8;
  const int bcol = (swz % gridDim.x) << 8;

  f32x4 acc[8][4];
#pragma unroll
  for (int f = 0; f < 8; ++f)
#pragma unroll
    for (int c = 0; c < 4; ++c)
      acc[f][c] = (f32x4){0.f, 0.f, 0.f, 0.f};

  const int NT = 16;
  stage_half(Ag, brow, 0, 0, 0, wid, lane, smem);
  stage_half(Bg, bcol, 0, 0, 1, wid, lane, smem);
  stage_half(Ag, brow, 0, 1, 2, wid, lane, smem);
  stage_half(Bg, bcol, 0, 1, 3, wid, lane, smem);
  stage_half(Ag, brow, 1, 0, 4, wid, lane, smem);
  stage_half(Bg, bcol, 1, 0, 5, wid, lane, smem);
  stage_half(Ag, brow, 1, 1, 6, wid, lane, smem);
  WAIT_VM6();
  GBAR();

  for (int t = 0; t < NT; ++t) {
    const int cur4 = (t & 1) * 4;
    const int nxt4 = cur4 ^ 4;
    short8 a[4], b[4];
#pragma unroll
    for (int f = 0; f < 4; ++f) a[f] = frag_ld(smem, cur4 + 0, wm * 128 + f * 16 + frow, kg);
#pragma unroll
    for (int c = 0; c < 4; ++c) b[c] = frag_ld(smem, cur4 + 1, wn * 64 + c * 16 + frow, kg);
    if (t + 1 < NT) stage_half(Bg, bcol, t + 1, 1, nxt4 + 3, wid, lane, smem);
    GBAR();
    __builtin_amdgcn_s_setprio(1);
#pragma unroll
    for (int f = 0; f < 4; ++f)
#pragma unroll
      for (int c = 0; c < 4; ++c)
        acc[f][c] = mma_h(a[f], b[c], acc[f][c]);
    __builtin_amdgcn_s_setprio(0);
    GBAR();
#pragma unroll
    for (int f = 0; f < 4; ++f) a[f] = frag_ld(smem, cur4 + 0, wm * 128 + (f + 4) * 16 + frow, kg);
    if (t + 2 < NT) stage_half(Ag, brow, t + 2, 0, cur4 + 0, wid, lane, smem);
    GBAR();
    __builtin_amdgcn_s_setprio(1);
#pragma unroll
    for (int f = 0; f < 4; ++f)
#pragma unroll
      for (int c = 0; c < 4; ++c)
        acc[f + 4][c] = mma_h(a[f], b[c], acc[f + 4][c]);
    __builtin_amdgcn_s_setprio(0);
    GBAR();
#pragma unroll
    for (int f = 0; f < 4; ++f) a[f] = frag_ld(smem, cur4 + 2, wm * 128 + f * 16 + frow, kg);
#pragma unroll
    for (int c = 0; c < 4; ++c) b[c] = frag_ld(smem, cur4 + 3, wn * 64 + c * 16 + frow, kg);
    if (t + 2 < NT) stage_half(Bg, bcol, t + 2, 0, cur4 + 1, wid, lane, smem);
    GBAR();
    __builtin_amdgcn_s_setprio(1);
#pragma unroll
    for (int f = 0; f < 4; ++f)
#pragma unroll
      for (int c = 0; c < 4; ++c)
        acc[f][c] = mma_h(a[f], b[c], acc[f][c]);
    __builtin_amdgcn_s_setprio(0);
    GBAR();
#pragma unroll
    for (int f = 0; f < 4; ++f) a[f] = frag_ld(smem, cur4 + 2, wm * 128 + (f + 4) * 16 + frow, kg);
    if (t + 2 < NT) stage_half(Ag, brow, t + 2, 1, cur4 + 2, wid, lane, smem);
    WAIT_VM6();
    GBAR();
    __builtin_amdgcn_s_setprio(1);
#pragma unroll
    for (int f = 0; f < 4; ++f)
#pragma unroll
      for (int c = 0; c < 4; ++c)
        acc[f + 4][c] = mma_h(a[f], b[c], acc[f + 4][c]);
    __builtin_amdgcn_s_setprio(0);
    GBAR();
  }
  WAIT_VM0();

#pragma unroll
  for (int f = 0; f < 8; ++f) {
    int r0 = brow + wm * 128 + f * 16 + kg * 4;
#pragma unroll
    for (int c = 0; c < 4; ++c) {
      int cc = bcol + wn * 64 + c * 16 + frow;
      float bb = bias[cc];
#pragma unroll
      for (int q = 0; q < 4; ++q)
        C[(size_t)(r0 + q) * H_DIM + cc] = acc[f][c][q] + bb;
    }
  }
}

// ---------------- WKV scan (fp64 state), windowed chunks over T ----------------
__global__ void wkv_scan_kernel(const float* __restrict__ kbuf,
                                const unsigned short* __restrict__ vrbuf,
                                const float* __restrict__ tdec,
                                unsigned short* __restrict__ rwh) {
  const int h = blockIdx.x * 64 + threadIdx.x;
  const int chunk = blockIdx.y;
  const int b = blockIdx.z;
  const int t0 = chunk * SCAN_C;
  const int tstart = (chunk == 0) ? 0 : (t0 - SCAN_W);
  const int tend = t0 + SCAN_C;
  double num, den;
  if (chunk == 0) { num = 1.0; den = 1.0; } else { num = 0.0; den = 0.0; }
  const double w = (double)tdec[h];
  size_t ik = ((size_t)b * T_DIM + tstart) * H_DIM + h;
  size_t iv = ((size_t)b * T_DIM + tstart) * 2048 + h;
  float kc = kbuf[ik];
  unsigned short vc = vrbuf[iv];
  unsigned short rc = vrbuf[iv + 1024];
  for (int t = tstart; t < tend; ++t) {
    int adv = (t + 1 < tend) ? 1 : 0;
    float kn = kbuf[ik + adv * H_DIM];
    unsigned short vn = vrbuf[iv + adv * 2048];
    unsigned short rn = vrbuf[iv + adv * 2048 + 1024];
    double ck = (double)kc;
    if (t >= t0) {
      double p = w * ck;
      double A = fma(p, den, num);
      double Bd = den + p;
      float outf = (float)A / (float)Bd;
      float rr = 1.0f / (1.0f + __expf(-h2f(rc)));
      rwh[ik] = f2h(rr * outf);
    }
    double ek = fast_exp64(ck);
    num = fma(w, num, ek * (double)h2f(vc));
    den = fma(w, den, ek);
    kc = kn; vc = vn; rc = rn;
    ik += H_DIM; iv += 2048;
  }
}

// -------------------------------- host --------------------------------
extern "C" void kernel_launch(void* const* d_in, const int* in_sizes, int n_in,
                              void* d_out, int out_size, void* d_ws, size_t ws_size,
                              hipStream_t stream) {
  const float* x    = (const float*)d_in[0];
  const float* tdec = (const float*)d_in[1];
  const float* tmk  = (const float*)d_in[2];
  const float* tmv  = (const float*)d_in[3];
  const float* tmr  = (const float*)d_in[4];
  const float* Wrec = (const float*)d_in[5];
  const float* Wkey = (const float*)d_in[6];
  const float* Wval = (const float*)d_in[7];
  const float* Wout = (const float*)d_in[8];
  const float* bout = (const float*)d_in[9];
  float* out = (float*)d_out;
  unsigned char* ws = (unsigned char*)d_ws;

  const size_t W2 = (size_t)H_DIM * H_DIM * 2;       // 2MB per fp16 weight
  const size_t BF_FULL = (size_t)M_DIM * H_DIM * 2;  // 32MB fp16 [M,H]
  const size_t NEED = 2 * BF_FULL + 2 * BF_FULL + 5 * W2;  // 138MB
  if (ws_size < NEED) return;

  size_t off = 0;
  unsigned short* XS1H = (unsigned short*)(ws + off); off += BF_FULL;
  unsigned short* XS2H = (unsigned short*)(ws + off); off += BF_FULL;
  unsigned short* VR   = (unsigned short*)(ws + off); off += 2 * BF_FULL;  // [M,2048] fp16
  unsigned short* WK1H = (unsigned short*)(ws + off); off += W2;
  unsigned short* WK2H = (unsigned short*)(ws + off); off += W2;
  unsigned short* WVRH = (unsigned short*)(ws + off); off += 2 * W2;       // [2048,1024] fp16
  unsigned short* WOH  = (unsigned short*)(ws + off); off += W2;

  wprep_kernel<<<dim3(H_DIM * H_DIM / 256), dim3(256), 0, stream>>>(
      Wrec, Wkey, Wval, Wout, tmk, tmv, tmr, WK1H, WK2H, WVRH, WOH);

  int n4 = M_DIM * (H_DIM / 4);
  xs_split_kernel<<<dim3(n4 / 256), dim3(256), 0, stream>>>(x, XS1H, XS2H, n4);

  // fused front: k (fp32 -> d_out) + v|r (fp16 -> VR) in one 1024-block dispatch
  front_kernel<<<dim3(1024), dim3(512), 0, stream>>>(
      XS1H, XS2H, WK1H, WK2H, WVRH, out, VR);

  // WKV scan; rw (fp16) reuses XS1H (dead after front)
  unsigned short* RWH = XS1H;
  wkv_scan_kernel<<<dim3(H_DIM / 64, T_DIM / SCAN_C, B_DIM), dim3(64), 0, stream>>>(
      out, VR, tdec, RWH);

  // final projection + bias -> d_out fp32
  gemm_o_kernel<<<dim3(H_DIM / 256, M_DIM / 256), dim3(512), 0, stream>>>(
      RWH, WOH, out, bout);
}

// Round 9
// 303.500 us; speedup vs baseline: 4.1757x; 1.0615x over previous
//
#include <hip/hip_runtime.h>

#define H_DIM 1024
#define T_DIM 4096
#define B_DIM 4
#define M_DIM (B_DIM * T_DIM)   // 16384
#define SCAN_C 64
#define SCAN_W 48

typedef __attribute__((ext_vector_type(8))) short short8;
typedef __attribute__((ext_vector_type(4))) float f32x4;
typedef _Float16 half8 __attribute__((ext_vector_type(8)));

__device__ __forceinline__ unsigned short f2h(float f) {
  _Float16 h = (_Float16)f;
  return __builtin_bit_cast(unsigned short, h);
}
__device__ __forceinline__ float h2f(unsigned short u) {
  return (float)__builtin_bit_cast(_Float16, u);
}

__device__ __forceinline__ double fast_exp64(double x) {
  const double L2E = 1.4426950408889634074;
  const double LN2 = 0.69314718055994530942;
  double z = x * L2E;
  double n = rint(z);
  double y = (z - n) * LN2;
  double p = 2.7557319223985890653e-6;
  p = fma(p, y, 2.4801587301587301566e-5);
  p = fma(p, y, 1.9841269841269841253e-4);
  p = fma(p, y, 1.3888888888888889419e-3);
  p = fma(p, y, 8.3333333333333332177e-3);
  p = fma(p, y, 4.1666666666666664354e-2);
  p = fma(p, y, 1.6666666666666665741e-1);
  p = fma(p, y, 0.5);
  p = fma(p, y, 1.0);
  p = fma(p, y, 1.0);
  long long bits = ((long long)(1023 + (int)n)) << 52;
  return p * __longlong_as_double(bits);
}

// ------- fused prep: xs split (blocks 0..16383) + weight prep (blocks 16384..20479) -------
__global__ void prep_kernel(const float* __restrict__ x,
                            const float* __restrict__ Wrec, const float* __restrict__ Wkey,
                            const float* __restrict__ Wval, const float* __restrict__ Wout,
                            const float* __restrict__ tmk, const float* __restrict__ tmv,
                            const float* __restrict__ tmr,
                            unsigned short* __restrict__ xs1, unsigned short* __restrict__ xs2,
                            unsigned short* __restrict__ WK1H, unsigned short* __restrict__ WK2H,
                            unsigned short* __restrict__ WVRH, unsigned short* __restrict__ WOH) {
  int bid = blockIdx.x;
  if (bid < 16384) {
    // xs = x + time_shift(x); scaled fp16 double-split (x1 + x2*2^-11)
    int i = bid * 256 + threadIdx.x;   // float4 index, n4 = 16384*256
    const int HV = H_DIM / 4;
    int m = i / HV;
    int t = m & (T_DIM - 1);
    float4 cur = reinterpret_cast<const float4*>(x)[i];
    float4 prev = make_float4(0.f, 0.f, 0.f, 0.f);
    if (t > 0) prev = reinterpret_cast<const float4*>(x)[i - HV];
    float s[4] = {cur.x + prev.x, cur.y + prev.y, cur.z + prev.z, cur.w + prev.w};
    unsigned short a1[4], a2[4];
#pragma unroll
    for (int q = 0; q < 4; ++q) {
      unsigned short h1 = f2h(s[q]);
      a1[q] = h1;
      a2[q] = f2h((s[q] - h2f(h1)) * 2048.0f);
    }
    reinterpret_cast<ushort4*>(xs1)[i] = make_ushort4(a1[0], a1[1], a1[2], a1[3]);
    reinterpret_cast<ushort4*>(xs2)[i] = make_ushort4(a2[0], a2[1], a2[2], a2[3]);
  } else {
    int i = (bid - 16384) * 256 + threadIdx.x;
    int j = i & (H_DIM - 1);
    float wk = Wkey[i] * tmk[j];
    unsigned short k1 = f2h(wk);
    WK1H[i] = k1;
    WK2H[i] = f2h((wk - h2f(k1)) * 2048.0f);
    WVRH[i] = f2h(Wval[i] * tmv[j]);                   // rows 0..1023: v-weights
    WVRH[H_DIM * H_DIM + i] = f2h(Wrec[i] * tmr[j]);  // rows 1024..2047: r-weights
    WOH[i] = f2h(Wout[i]);
  }
}

// ------------------------- shared helpers -------------------------
#define GBAR() do { asm volatile("" ::: "memory"); __builtin_amdgcn_sched_barrier(0); \
                    __builtin_amdgcn_s_barrier(); \
                    __builtin_amdgcn_sched_barrier(0); asm volatile("" ::: "memory"); } while (0)
#define WAIT_VM6() asm volatile("s_waitcnt vmcnt(6)" ::: "memory")
#define WAIT_VM0() asm volatile("s_waitcnt vmcnt(0)" ::: "memory")

__device__ __forceinline__ f32x4 mma_h(short8 a, short8 b, f32x4 c) {
  return __builtin_amdgcn_mfma_f32_16x16x32_f16(
      __builtin_bit_cast(half8, a), __builtin_bit_cast(half8, b), c, 0, 0, 0);
}

// stage 128 rows x 32 cols (8KB): 1 load/thread; linear LDS, inverse-swz source
__device__ __forceinline__ void stage_r128(const unsigned short* base, int rowoff, int kt,
                                           unsigned dst, int wid, int lane,
                                           unsigned char* smem) {
  int row = wid * 16 + (lane >> 2);
  int col8 = (lane & 3) ^ ((row >> 1) & 3);
  const unsigned short* src = base + (size_t)(rowoff + row) * 1024 + kt * 32 + col8 * 8;
  __builtin_amdgcn_global_load_lds(
      (const __attribute__((address_space(1))) void*)src,
      (__attribute__((address_space(3))) void*)(smem + dst + wid * 1024), 16, 0, 0);
}
// stage 256 rows x 32 cols (16KB): 2 loads/thread
__device__ __forceinline__ void stage_r256(const unsigned short* base, int rowoff, int kt,
                                           unsigned dst, int wid, int lane,
                                           unsigned char* smem) {
#pragma unroll
  for (int i = 0; i < 2; ++i) {
    int row = wid * 32 + i * 16 + (lane >> 2);
    int col8 = (lane & 3) ^ ((row >> 1) & 3);
    const unsigned short* src = base + (size_t)(rowoff + row) * 1024 + kt * 32 + col8 * 8;
    __builtin_amdgcn_global_load_lds(
        (const __attribute__((address_space(1))) void*)src,
        (__attribute__((address_space(3))) void*)(smem + dst + wid * 2048 + i * 1024), 16, 0, 0);
  }
}
__device__ __forceinline__ short8 frag_ld2(const unsigned char* smem, unsigned rbase,
                                           int row, int kg) {
  return *reinterpret_cast<const short8*>(smem + rbase + row * 64 + ((kg ^ ((row >> 1) & 3)) * 16));
}

// ============ k-role: 128x256 tile, 3-combo fp32-emulated GEMM, 2 phases/tile ============
// k ~= A1B1 + 2^-11*(A1B2 + A2B1)  [cross-residual term A2B2*2^-22 ~1e-7 << fp32-acc
// rounding ~3e-7, dropped].  BK=32, 3-slot LDS ring, 2-tile lead, vmcnt(6)/tile.
__device__ void gemm_k_body(const unsigned short* __restrict__ A1,
                            const unsigned short* __restrict__ A2,
                            const unsigned short* __restrict__ B1,
                            const unsigned short* __restrict__ B2,
                            float* __restrict__ C, int bid, unsigned char* smem) {
  const int tid = threadIdx.x;
  const int wid = tid >> 6;
  const int lane = tid & 63;
  const int wm = wid >> 2;   // 0..1 -> 64 rows each
  const int wn = wid & 3;    // 0..3 -> 64 cols each
  const int frow = lane & 15;
  const int kg = lane >> 4;
  const int swz = (bid & 7) * 64 + (bid >> 3);   // nwg=512, bijective
  const int brow = (swz >> 2) << 7;   // 128-row tile
  const int bcol = (swz & 3) << 8;    // 256-col tile

  f32x4 acc0[4][4], acc1[4][4];
#pragma unroll
  for (int f = 0; f < 4; ++f)
#pragma unroll
    for (int c = 0; c < 4; ++c) {
      acc0[f][c] = (f32x4){0.f, 0.f, 0.f, 0.f};
      acc1[f][c] = (f32x4){0.f, 0.f, 0.f, 0.f};
    }

  const int NT = 32;  // K=1024 / BK=32
#pragma unroll
  for (int t0 = 0; t0 < 2; ++t0) {
    unsigned sb = t0 * 49152u;
    stage_r128(A1, brow, t0, sb + 0u, wid, lane, smem);
    stage_r128(A2, brow, t0, sb + 8192u, wid, lane, smem);
    stage_r256(B1, bcol, t0, sb + 16384u, wid, lane, smem);
    stage_r256(B2, bcol, t0, sb + 32768u, wid, lane, smem);
  }
  WAIT_VM6();
  GBAR();

  for (int t = 0; t < NT; ++t) {
    unsigned sb = (unsigned)(t % 3) * 49152u;
    unsigned st = (unsigned)((t + 2) % 3) * 49152u;
    const bool stg = (t + 2 < NT);
    short8 a1[4], a2[4], b1[4], b2[4];
    // ---- P0: read a1,b1,b2 (12); stage A1,A2(t+2); 32 MFMA ----
#pragma unroll
    for (int f = 0; f < 4; ++f) a1[f] = frag_ld2(smem, sb + 0u, wm * 64 + f * 16 + frow, kg);
#pragma unroll
    for (int c = 0; c < 4; ++c) b1[c] = frag_ld2(smem, sb + 16384u, wn * 64 + c * 16 + frow, kg);
#pragma unroll
    for (int c = 0; c < 4; ++c) b2[c] = frag_ld2(smem, sb + 32768u, wn * 64 + c * 16 + frow, kg);
    if (stg) {
      stage_r128(A1, brow, t + 2, st + 0u, wid, lane, smem);
      stage_r128(A2, brow, t + 2, st + 8192u, wid, lane, smem);
    }
    GBAR();
    __builtin_amdgcn_s_setprio(1);
#pragma unroll
    for (int f = 0; f < 4; ++f)
#pragma unroll
      for (int c = 0; c < 4; ++c)
        acc0[f][c] = mma_h(a1[f], b1[c], acc0[f][c]);
#pragma unroll
    for (int f = 0; f < 4; ++f)
#pragma unroll
      for (int c = 0; c < 4; ++c)
        acc1[f][c] = mma_h(a1[f], b2[c], acc1[f][c]);
    __builtin_amdgcn_s_setprio(0);
    GBAR();
    // ---- P1: read a2 (4); stage B1,B2(t+2); vmcnt(6); 16 MFMA ----
#pragma unroll
    for (int f = 0; f < 4; ++f) a2[f] = frag_ld2(smem, sb + 8192u, wm * 64 + f * 16 + frow, kg);
    if (stg) {
      stage_r256(B1, bcol, t + 2, st + 16384u, wid, lane, smem);
      stage_r256(B2, bcol, t + 2, st + 32768u, wid, lane, smem);
    }
    WAIT_VM6();
    GBAR();
    __builtin_amdgcn_s_setprio(1);
#pragma unroll
    for (int f = 0; f < 4; ++f)
#pragma unroll
      for (int c = 0; c < 4; ++c)
        acc1[f][c] = mma_h(a2[f], b1[c], acc1[f][c]);
    __builtin_amdgcn_s_setprio(0);
    GBAR();
  }
  WAIT_VM0();

  // out = acc0 + 2^-11*acc1; C/D layout col=lane&15, row=(lane>>4)*4+q
#pragma unroll
  for (int f = 0; f < 4; ++f) {
    int r0 = brow + wm * 64 + f * 16 + kg * 4;
#pragma unroll
    for (int c = 0; c < 4; ++c) {
      int cc = bcol + wn * 64 + c * 16 + frow;
#pragma unroll
      for (int q = 0; q < 4; ++q)
        C[(size_t)(r0 + q) * H_DIM + cc] =
            fmaf(0.00048828125f, acc1[f][c][q], acc0[f][c][q]);
    }
  }
}

// ============ vr-role: 256x256 8-phase fp16 GEMM, N=2048, fp16 out ============
__device__ __forceinline__ void stage_half(const unsigned short* base, int rowoff,
                                           int ktp, int kk, int slot,
                                           int wid, int lane, unsigned char* smem) {
#pragma unroll
  for (int i = 0; i < 2; ++i) {
    int row = wid * 32 + i * 16 + (lane >> 2);
    int kcol8 = (lane & 3) ^ ((row >> 1) & 3);
    const unsigned short* src = base + (size_t)(rowoff + row) * 1024
                                + ktp * 64 + kk * 32 + kcol8 * 8;
    unsigned int doff = (unsigned int)(slot * 16384 + wid * 2048 + i * 1024);
    __builtin_amdgcn_global_load_lds(
        (const __attribute__((address_space(1))) void*)src,
        (__attribute__((address_space(3))) void*)(smem + doff), 16, 0, 0);
  }
}
__device__ __forceinline__ short8 frag_ld(const unsigned char* smem, int slot, int row, int kg) {
  int byte = slot * 16384 + row * 64 + ((kg ^ ((row >> 1) & 3)) * 16);
  return *reinterpret_cast<const short8*>(smem + byte);
}

__device__ void gemm_vr_body(const unsigned short* __restrict__ Ag,
                             const unsigned short* __restrict__ Bg,
                             unsigned short* __restrict__ C, int bid,
                             unsigned char* smem) {
  const int tid = threadIdx.x;
  const int wid = tid >> 6;
  const int lane = tid & 63;
  const int wm = wid >> 2;
  const int wn = wid & 3;
  const int frow = lane & 15;
  const int kg = lane >> 4;
  const int swz = (bid & 7) * 64 + (bid >> 3);   // nwg=512
  const int brow = (swz >> 3) << 8;   // 64 row-blocks
  const int bcol = (swz & 7) << 8;    // 8 col-blocks (N=2048)

  f32x4 acc[8][4];
#pragma unroll
  for (int f = 0; f < 8; ++f)
#pragma unroll
    for (int c = 0; c < 4; ++c)
      acc[f][c] = (f32x4){0.f, 0.f, 0.f, 0.f};

  const int NT = 16;
  stage_half(Ag, brow, 0, 0, 0, wid, lane, smem);
  stage_half(Bg, bcol, 0, 0, 1, wid, lane, smem);
  stage_half(Ag, brow, 0, 1, 2, wid, lane, smem);
  stage_half(Bg, bcol, 0, 1, 3, wid, lane, smem);
  stage_half(Ag, brow, 1, 0, 4, wid, lane, smem);
  stage_half(Bg, bcol, 1, 0, 5, wid, lane, smem);
  stage_half(Ag, brow, 1, 1, 6, wid, lane, smem);
  WAIT_VM6();
  GBAR();

  for (int t = 0; t < NT; ++t) {
    const int cur4 = (t & 1) * 4;
    const int nxt4 = cur4 ^ 4;
    short8 a[4], b[4];
#pragma unroll
    for (int f = 0; f < 4; ++f) a[f] = frag_ld(smem, cur4 + 0, wm * 128 + f * 16 + frow, kg);
#pragma unroll
    for (int c = 0; c < 4; ++c) b[c] = frag_ld(smem, cur4 + 1, wn * 64 + c * 16 + frow, kg);
    if (t + 1 < NT) stage_half(Bg, bcol, t + 1, 1, nxt4 + 3, wid, lane, smem);
    GBAR();
    __builtin_amdgcn_s_setprio(1);
#pragma unroll
    for (int f = 0; f < 4; ++f)
#pragma unroll
      for (int c = 0; c < 4; ++c)
        acc[f][c] = mma_h(a[f], b[c], acc[f][c]);
    __builtin_amdgcn_s_setprio(0);
    GBAR();
#pragma unroll
    for (int f = 0; f < 4; ++f) a[f] = frag_ld(smem, cur4 + 0, wm * 128 + (f + 4) * 16 + frow, kg);
    if (t + 2 < NT) stage_half(Ag, brow, t + 2, 0, cur4 + 0, wid, lane, smem);
    GBAR();
    __builtin_amdgcn_s_setprio(1);
#pragma unroll
    for (int f = 0; f < 4; ++f)
#pragma unroll
      for (int c = 0; c < 4; ++c)
        acc[f + 4][c] = mma_h(a[f], b[c], acc[f + 4][c]);
    __builtin_amdgcn_s_setprio(0);
    GBAR();
#pragma unroll
    for (int f = 0; f < 4; ++f) a[f] = frag_ld(smem, cur4 + 2, wm * 128 + f * 16 + frow, kg);
#pragma unroll
    for (int c = 0; c < 4; ++c) b[c] = frag_ld(smem, cur4 + 3, wn * 64 + c * 16 + frow, kg);
    if (t + 2 < NT) stage_half(Bg, bcol, t + 2, 0, cur4 + 1, wid, lane, smem);
    GBAR();
    __builtin_amdgcn_s_setprio(1);
#pragma unroll
    for (int f = 0; f < 4; ++f)
#pragma unroll
      for (int c = 0; c < 4; ++c)
        acc[f][c] = mma_h(a[f], b[c], acc[f][c]);
    __builtin_amdgcn_s_setprio(0);
    GBAR();
#pragma unroll
    for (int f = 0; f < 4; ++f) a[f] = frag_ld(smem, cur4 + 2, wm * 128 + (f + 4) * 16 + frow, kg);
    if (t + 2 < NT) stage_half(Ag, brow, t + 2, 1, cur4 + 2, wid, lane, smem);
    WAIT_VM6();
    GBAR();
    __builtin_amdgcn_s_setprio(1);
#pragma unroll
    for (int f = 0; f < 4; ++f)
#pragma unroll
      for (int c = 0; c < 4; ++c)
        acc[f + 4][c] = mma_h(a[f], b[c], acc[f + 4][c]);
    __builtin_amdgcn_s_setprio(0);
    GBAR();
  }
  WAIT_VM0();

#pragma unroll
  for (int f = 0; f < 8; ++f) {
    int r0 = brow + wm * 128 + f * 16 + kg * 4;
#pragma unroll
    for (int c = 0; c < 4; ++c) {
      int cc = bcol + wn * 64 + c * 16 + frow;
#pragma unroll
      for (int q = 0; q < 4; ++q)
        C[(size_t)(r0 + q) * 2048 + cc] = f2h(acc[f][c][q]);
    }
  }
}

// fused front dispatch: blocks 0..511 compute k (fp32 -> Ck), 512..1023 compute v|r (fp16 -> Cvr)
__global__ __launch_bounds__(512, 2) void front_kernel(
    const unsigned short* __restrict__ XS1, const unsigned short* __restrict__ XS2,
    const unsigned short* __restrict__ WK1, const unsigned short* __restrict__ WK2,
    const unsigned short* __restrict__ WVR,
    float* __restrict__ Ck, unsigned short* __restrict__ Cvr) {
  __shared__ __attribute__((aligned(16))) unsigned char smem[147456];
  int bid = blockIdx.x;
  if (bid < 512)
    gemm_k_body(XS1, XS2, WK1, WK2, Ck, bid, smem);
  else
    gemm_vr_body(XS1, WVR, Cvr, bid - 512, smem);
}

// =================== Po: 256x256 8-phase fp16 GEMM, fp32 out + bias ===================
__global__ __launch_bounds__(512, 2) void gemm_o_kernel(const unsigned short* __restrict__ Ag,
                                                        const unsigned short* __restrict__ Bg,
                                                        float* __restrict__ C,
                                                        const float* __restrict__ bias) {
  __shared__ __attribute__((aligned(16))) unsigned char smem[131072];
  const int tid = threadIdx.x;
  const int wid = tid >> 6;
  const int lane = tid & 63;
  const int wm = wid >> 2;
  const int wn = wid & 3;
  const int frow = lane & 15;
  const int kg = lane >> 4;
  const int nwg = gridDim.x * gridDim.y;   // 256
  const int wg = blockIdx.y * gridDim.x + blockIdx.x;
  const int swz = (wg & 7) * (nwg >> 3) + (wg >> 3);
  const int brow = (swz / gridDim.x) << 8;
  const int bcol = (swz % gridDim.x) << 8;

  f32x4 acc[8][4];
#pragma unroll
  for (int f = 0; f < 8; ++f)
#pragma unroll
    for (int c = 0; c < 4; ++c)
      acc[f][c] = (f32x4){0.f, 0.f, 0.f, 0.f};

  const int NT = 16;
  stage_half(Ag, brow, 0, 0, 0, wid, lane, smem);
  stage_half(Bg, bcol, 0, 0, 1, wid, lane, smem);
  stage_half(Ag, brow, 0, 1, 2, wid, lane, smem);
  stage_half(Bg, bcol, 0, 1, 3, wid, lane, smem);
  stage_half(Ag, brow, 1, 0, 4, wid, lane, smem);
  stage_half(Bg, bcol, 1, 0, 5, wid, lane, smem);
  stage_half(Ag, brow, 1, 1, 6, wid, lane, smem);
  WAIT_VM6();
  GBAR();

  for (int t = 0; t < NT; ++t) {
    const int cur4 = (t & 1) * 4;
    const int nxt4 = cur4 ^ 4;
    short8 a[4], b[4];
#pragma unroll
    for (int f = 0; f < 4; ++f) a[f] = frag_ld(smem, cur4 + 0, wm * 128 + f * 16 + frow, kg);
#pragma unroll
    for (int c = 0; c < 4; ++c) b[c] = frag_ld(smem, cur4 + 1, wn * 64 + c * 16 + frow, kg);
    if (t + 1 < NT) stage_half(Bg, bcol, t + 1, 1, nxt4 + 3, wid, lane, smem);
    GBAR();
    __builtin_amdgcn_s_setprio(1);
#pragma unroll
    for (int f = 0; f < 4; ++f)
#pragma unroll
      for (int c = 0; c < 4; ++c)
        acc[f][c] = mma_h(a[f], b[c], acc[f][c]);
    __builtin_amdgcn_s_setprio(0);
    GBAR();
#pragma unroll
    for (int f = 0; f < 4; ++f) a[f] = frag_ld(smem, cur4 + 0, wm * 128 + (f + 4) * 16 + frow, kg);
    if (t + 2 < NT) stage_half(Ag, brow, t + 2, 0, cur4 + 0, wid, lane, smem);
    GBAR();
    __builtin_amdgcn_s_setprio(1);
#pragma unroll
    for (int f = 0; f < 4; ++f)
#pragma unroll
      for (int c = 0; c < 4; ++c)
        acc[f + 4][c] = mma_h(a[f], b[c], acc[f + 4][c]);
    __builtin_amdgcn_s_setprio(0);
    GBAR();
#pragma unroll
    for (int f = 0; f < 4; ++f) a[f] = frag_ld(smem, cur4 + 2, wm * 128 + f * 16 + frow, kg);
#pragma unroll
    for (int c = 0; c < 4; ++c) b[c] = frag_ld(smem, cur4 + 3, wn * 64 + c * 16 + frow, kg);
    if (t + 2 < NT) stage_half(Bg, bcol, t + 2, 0, cur4 + 1, wid, lane, smem);
    GBAR();
    __builtin_amdgcn_s_setprio(1);
#pragma unroll
    for (int f = 0; f < 4; ++f)
#pragma unroll
      for (int c = 0; c < 4; ++c)
        acc[f][c] = mma_h(a[f], b[c], acc[f][c]);
    __builtin_amdgcn_s_setprio(0);
    GBAR();
#pragma unroll
    for (int f = 0; f < 4; ++f) a[f] = frag_ld(smem, cur4 + 2, wm * 128 + (f + 4) * 16 + frow, kg);
    if (t + 2 < NT) stage_half(Ag, brow, t + 2, 1, cur4 + 2, wid, lane, smem);
    WAIT_VM6();
    GBAR();
    __builtin_amdgcn_s_setprio(1);
#pragma unroll
    for (int f = 0; f < 4; ++f)
#pragma unroll
      for (int c = 0; c < 4; ++c)
        acc[f + 4][c] = mma_h(a[f], b[c], acc[f + 4][c]);
    __builtin_amdgcn_s_setprio(0);
    GBAR();
  }
  WAIT_VM0();

#pragma unroll
  for (int f = 0; f < 8; ++f) {
    int r0 = brow + wm * 128 + f * 16 + kg * 4;
#pragma unroll
    for (int c = 0; c < 4; ++c) {
      int cc = bcol + wn * 64 + c * 16 + frow;
      float bb = bias[cc];
#pragma unroll
      for (int q = 0; q < 4; ++q)
        C[(size_t)(r0 + q) * H_DIM + cc] = acc[f][c][q] + bb;
    }
  }
}

// ---------------- WKV scan (fp64 state), ILP-2: each lane owns 2 adjacent channels ----------------
__global__ void wkv_scan_kernel(const float* __restrict__ kbuf,
                                const unsigned short* __restrict__ vrbuf,
                                const float* __restrict__ tdec,
                                unsigned short* __restrict__ rwh) {
  const int h = (blockIdx.x * 64 + threadIdx.x) * 2;
  const int chunk = blockIdx.y;
  const int b = blockIdx.z;
  const int t0 = chunk * SCAN_C;
  const int tstart = (chunk == 0) ? 0 : (t0 - SCAN_W);
  const int tend = t0 + SCAN_C;
  double num0, den0, num1, den1;
  if (chunk == 0) { num0 = num1 = 1.0; den0 = den1 = 1.0; }
  else            { num0 = num1 = 0.0; den0 = den1 = 0.0; }
  const double w0 = (double)tdec[h];
  const double w1 = (double)tdec[h + 1];
  size_t ik = ((size_t)b * T_DIM + tstart) * H_DIM + h;
  size_t iv = ((size_t)b * T_DIM + tstart) * 2048 + h;
  float2 kc = *reinterpret_cast<const float2*>(kbuf + ik);
  unsigned int vc = *reinterpret_cast<const unsigned int*>(vrbuf + iv);
  unsigned int rc = *reinterpret_cast<const unsigned int*>(vrbuf + iv + 1024);
  for (int t = tstart; t < tend; ++t) {
    size_t adv = (t + 1 < tend) ? 1 : 0;
    float2 kn = *reinterpret_cast<const float2*>(kbuf + ik + adv * H_DIM);
    unsigned int vn = *reinterpret_cast<const unsigned int*>(vrbuf + iv + adv * 2048);
    unsigned int rn = *reinterpret_cast<const unsigned int*>(vrbuf + iv + adv * 2048 + 1024);
    double ck0 = (double)kc.x, ck1 = (double)kc.y;
    if (t >= t0) {
      double p0 = w0 * ck0, p1 = w1 * ck1;
      float o0 = (float)fma(p0, den0, num0) / (float)(den0 + p0);
      float o1 = (float)fma(p1, den1, num1) / (float)(den1 + p1);
      float rr0 = 1.0f / (1.0f + __expf(-h2f((unsigned short)(rc & 0xffffu))));
      float rr1 = 1.0f / (1.0f + __expf(-h2f((unsigned short)(rc >> 16))));
      unsigned int wout = (unsigned int)f2h(rr0 * o0) | ((unsigned int)f2h(rr1 * o1) << 16);
      *reinterpret_cast<unsigned int*>(rwh + ik) = wout;
    }
    double ek0 = fast_exp64(ck0);
    double ek1 = fast_exp64(ck1);
    num0 = fma(w0, num0, ek0 * (double)h2f((unsigned short)(vc & 0xffffu)));
    den0 = fma(w0, den0, ek0);
    num1 = fma(w1, num1, ek1 * (double)h2f((unsigned short)(vc >> 16)));
    den1 = fma(w1, den1, ek1);
    kc = kn; vc = vn; rc = rn;
    ik += H_DIM; iv += 2048;
  }
}

// -------------------------------- host --------------------------------
extern "C" void kernel_launch(void* const* d_in, const int* in_sizes, int n_in,
                              void* d_out, int out_size, void* d_ws, size_t ws_size,
                              hipStream_t stream) {
  const float* x    = (const float*)d_in[0];
  const float* tdec = (const float*)d_in[1];
  const float* tmk  = (const float*)d_in[2];
  const float* tmv  = (const float*)d_in[3];
  const float* tmr  = (const float*)d_in[4];
  const float* Wrec = (const float*)d_in[5];
  const float* Wkey = (const float*)d_in[6];
  const float* Wval = (const float*)d_in[7];
  const float* Wout = (const float*)d_in[8];
  const float* bout = (const float*)d_in[9];
  float* out = (float*)d_out;
  unsigned char* ws = (unsigned char*)d_ws;

  const size_t W2 = (size_t)H_DIM * H_DIM * 2;       // 2MB per fp16 weight
  const size_t BF_FULL = (size_t)M_DIM * H_DIM * 2;  // 32MB fp16 [M,H]
  const size_t NEED = 2 * BF_FULL + 2 * BF_FULL + 5 * W2;  // 138MB
  if (ws_size < NEED) return;

  size_t off = 0;
  unsigned short* XS1H = (unsigned short*)(ws + off); off += BF_FULL;
  unsigned short* XS2H = (unsigned short*)(ws + off); off += BF_FULL;
  unsigned short* VR   = (unsigned short*)(ws + off); off += 2 * BF_FULL;  // [M,2048] fp16
  unsigned short* WK1H = (unsigned short*)(ws + off); off += W2;
  unsigned short* WK2H = (unsigned short*)(ws + off); off += W2;
  unsigned short* WVRH = (unsigned short*)(ws + off); off += 2 * W2;       // [2048,1024] fp16
  unsigned short* WOH  = (unsigned short*)(ws + off); off += W2;

  // fused prep: xs split + weight prep in one dispatch
  prep_kernel<<<dim3(16384 + 4096), dim3(256), 0, stream>>>(
      x, Wrec, Wkey, Wval, Wout, tmk, tmv, tmr, XS1H, XS2H, WK1H, WK2H, WVRH, WOH);

  // fused front: k (fp32 -> d_out) + v|r (fp16 -> VR) in one 1024-block dispatch
  front_kernel<<<dim3(1024), dim3(512), 0, stream>>>(
      XS1H, XS2H, WK1H, WK2H, WVRH, out, VR);

  // WKV scan (ILP-2); rw (fp16) reuses XS1H (dead after front)
  unsigned short* RWH = XS1H;
  wkv_scan_kernel<<<dim3(H_DIM / 128, T_DIM / SCAN_C, B_DIM), dim3(64), 0, stream>>>(
      out, VR, tdec, RWH);

  // final projection + bias -> d_out fp32
  gemm_o_kernel<<<dim3(H_DIM / 256, M_DIM / 256), dim3(512), 0, stream>>>(
      RWH, WOH, out, bout);
}